// Round 2
// baseline (1670.841 us; speedup 1.0000x reference)
//
#include <hip/hip_runtime.h>
#include <hip/hip_fp16.h>
#include <cstddef>
#include <cstdint>

#define BB 16384
#define DIMG 2048
#define HH 512
#define VOCAB 200
#define TT 20

using frag16 = __attribute__((ext_vector_type(8))) short;   // 8 x bf16 (4 VGPRs)
using f32x4v = __attribute__((ext_vector_type(4))) float;   // MFMA accumulator

#define MFMA16(a, b, c) __builtin_amdgcn_mfma_f32_16x16x32_bf16((a), (b), (c), 0, 0, 0)

__device__ __forceinline__ float bf2f(unsigned short u) {
    union { unsigned int i; float f; } c; c.i = ((unsigned int)u) << 16; return c.f;
}
__device__ __forceinline__ unsigned short f2bf(float f) {
    union { float f; unsigned int i; } c; c.f = f;
    unsigned int u = c.i;
    u = (u + 0x7FFFu + ((u >> 16) & 1u)) >> 16;   // RTNE
    return (unsigned short)u;
}
__device__ __forceinline__ float sigf(float x) { return 1.f / (1.f + __expf(-x)); }
__device__ __forceinline__ float ftanh(float x) {
    return 1.f - 2.f / (1.f + __expf(2.f * x));   // saturates correctly at +-inf
}
// async global->LDS, 16B/lane; LDS dest = wave-uniform base + lane*16
__device__ __forceinline__ void gload16(const void* g, void* l) {
    __builtin_amdgcn_global_load_lds(
        (__attribute__((address_space(1))) void*)g,
        (__attribute__((address_space(3))) void*)l, 16, 0, 0);
}

// ---------------------------------------------------------------------------
// bf16 MFMA GEMM for encoder: C = act(A[M,K] @ W[N,K]^T + bias).
// OM: 0=f32, 1=bf16, 2=f16 output.
// ---------------------------------------------------------------------------
template<int ACT, int OM>
__global__ __launch_bounds__(256) void gemm_bt_mfma(
    const unsigned short* __restrict__ A, const unsigned short* __restrict__ W,
    const float* __restrict__ bias, void* __restrict__ Cv, int M, int N, int K)
{
    __shared__ unsigned short As[128 * 32];
    __shared__ unsigned short Ws[128 * 32];
    const int t = threadIdx.x;
    const int lane = t & 63, w = t >> 6;
    const int bm = blockIdx.x, bn = blockIdx.y;
    const int wm = (w >> 1) * 64, wn = (w & 1) * 64;

    f32x4v acc[4][4];
    #pragma unroll
    for (int i = 0; i < 4; ++i)
        #pragma unroll
        for (int j = 0; j < 4; ++j)
            #pragma unroll
            for (int r = 0; r < 4; ++r) acc[i][j][r] = 0.f;

    const unsigned short* Ag  = A + (size_t)(bm * 128 + (t >> 2)) * K + (t & 3) * 8;
    const unsigned short* Ag2 = A + (size_t)(bm * 128 + 64 + (t >> 2)) * K + (t & 3) * 8;
    const unsigned short* Wg  = W + (size_t)(bn * 128 + (t >> 2)) * K + (t & 3) * 8;
    const unsigned short* Wg2 = W + (size_t)(bn * 128 + 64 + (t >> 2)) * K + (t & 3) * 8;
    char* AsB = (char*)As; char* WsB = (char*)Ws;

    const int kIters = K >> 5;
    for (int ki = 0; ki < kIters; ++ki) {
        const int k0 = ki * 32;
        gload16(Ag  + k0, AsB + w * 1024);
        gload16(Ag2 + k0, AsB + 4096 + w * 1024);
        gload16(Wg  + k0, WsB + w * 1024);
        gload16(Wg2 + k0, WsB + 4096 + w * 1024);
        __syncthreads();
        frag16 af[4], bf[4];
        #pragma unroll
        for (int i = 0; i < 4; ++i) {
            af[i] = *(const frag16*)(AsB + (wm + i * 16 + (lane & 15)) * 64 + (lane >> 4) * 16);
            bf[i] = *(const frag16*)(WsB + (wn + i * 16 + (lane & 15)) * 64 + (lane >> 4) * 16);
        }
        #pragma unroll
        for (int i = 0; i < 4; ++i)
            #pragma unroll
            for (int j = 0; j < 4; ++j)
                acc[i][j] = MFMA16(af[i], bf[j], acc[i][j]);
        __syncthreads();
    }

    #pragma unroll
    for (int j = 0; j < 4; ++j) {
        const int gn = bn * 128 + wn + j * 16 + (lane & 15);
        const float bv = bias[gn];
        #pragma unroll
        for (int i = 0; i < 4; ++i) {
            #pragma unroll
            for (int r = 0; r < 4; ++r) {
                const size_t gm = (size_t)(bm * 128 + wm + i * 16 + (lane >> 4) * 4 + r);
                float v = acc[i][j][r] + bv;
                if (ACT == 1) v = fmaxf(v, 0.f);
                if (OM == 0)      ((float*)Cv)[gm * N + gn] = v;
                else if (OM == 1) ((unsigned short*)Cv)[gm * N + gn] = f2bf(v);
                else              ((__half*)Cv)[gm * N + gn] = __float2half(v);
            }
        }
    }
}

// ---------------------------------------------------------------------------
// GRU step body, tile 128 rows x 64 h-cols (x3 gates), BK=64. 256 threads.
// A (h rows) is loaded DIRECTLY global->registers: wave w's lane (q,m) needs
// exactly h[bm*128 + half*64 + w*16 + m][k0 + kk*32 + q*8 .. +7] = one 16B
// frag16 (16 rows x 64B contiguous per wave; h is 16MB -> L2/L3-resident).
// Only W (whh, 3 gates) goes through LDS: 24KB per K-iter, 6 DMA/wave to
// drain per barrier (was 10). LDS total 32KB (epilogue reuses the region)
// -> 4 blocks/CU.
// Epilogue: two 64-row passes; each stages xg (3x8KB fp16) + h_old (8KB)
// into L[0..32KB), gate math from LDS, h_out repacked -> coalesced stores.
// ---------------------------------------------------------------------------
__device__ __forceinline__ void gru_body(
    unsigned short* lds,
    const unsigned short* __restrict__ hb, unsigned short* __restrict__ hob,
    const unsigned short* __restrict__ whhb, const float* __restrict__ bhh,
    const __half* __restrict__ xg, int bm, int bn, int t)
{
    char* L = (char*)lds;
    const int lane = t & 63, w = t >> 6;
    const int q = lane >> 4, m = lane & 15;

    f32x4v acc[2][3][4];
    #pragma unroll
    for (int i = 0; i < 2; ++i)
        #pragma unroll
        for (int g = 0; g < 3; ++g)
            #pragma unroll
            for (int j = 0; j < 4; ++j)
                #pragma unroll
                for (int r = 0; r < 4; ++r) acc[i][g][j][r] = 0.f;

    // ---- A-fragment direct global addresses (per-lane) ----
    const unsigned short* A0 = hb + (size_t)(bm * 128 + w * 16 + m) * HH + q * 8;
    const unsigned short* A1 = A0 + (size_t)64 * HH;

    // ---- W staging addresses (per-lane source for global_load_lds) ----
    const unsigned short* Wg0 = whhb + (size_t)(0 * HH + bn * 64 + (t >> 2)) * HH + (t & 3) * 8;
    const unsigned short* Wg1 = whhb + (size_t)(1 * HH + bn * 64 + (t >> 2)) * HH + (t & 3) * 8;
    const unsigned short* Wg2 = whhb + (size_t)(2 * HH + bn * 64 + (t >> 2)) * HH + (t & 3) * 8;

    for (int ki = 0; ki < 8; ++ki) {
        const int k0 = ki * 64;
        // W tile: [kk half 12KB][gate 4KB]
        gload16(Wg0 + k0,      L + w * 1024);
        gload16(Wg0 + k0 + 32, L + 12288 + w * 1024);
        gload16(Wg1 + k0,      L + 4096 + w * 1024);
        gload16(Wg1 + k0 + 32, L + 12288 + 4096 + w * 1024);
        gload16(Wg2 + k0,      L + 8192 + w * 1024);
        gload16(Wg2 + k0 + 32, L + 12288 + 8192 + w * 1024);
        // A fragments: latency overlaps the W DMA drain
        frag16 af[2][2];
        af[0][0] = *(const frag16*)(A0 + k0);
        af[0][1] = *(const frag16*)(A0 + k0 + 32);
        af[1][0] = *(const frag16*)(A1 + k0);
        af[1][1] = *(const frag16*)(A1 + k0 + 32);
        __syncthreads();
        #pragma unroll
        for (int kk = 0; kk < 2; ++kk) {
            #pragma unroll
            for (int g = 0; g < 3; ++g)
                #pragma unroll
                for (int j = 0; j < 4; ++j) {
                    frag16 bf = *(const frag16*)(L + kk * 12288 + g * 4096 + (j * 16 + m) * 64 + q * 16);
                    acc[0][g][j] = MFMA16(af[0][kk], bf, acc[0][g][j]);
                    acc[1][g][j] = MFMA16(af[1][kk], bf, acc[1][g][j]);
                }
        }
        __syncthreads();
    }

    // biases: same columns for both row-halves -> hoist
    float br[4], bz[4], bnn[4];
    #pragma unroll
    for (int j = 0; j < 4; ++j) {
        const int gc = bn * 64 + j * 16 + m;
        br[j] = bhh[gc]; bz[j] = bhh[HH + gc]; bnn[j] = bhh[2 * HH + gc];
    }

    #pragma unroll
    for (int half = 0; half < 2; ++half) {
        const int rbase = bm * 128 + half * 64;
        // ---- epilogue DMA: xg tiles at L+g*8192, h_old at L+24576 ----
        const __half* Xg = xg + (size_t)(rbase + (t >> 3)) * (3 * HH) + bn * 64 + (t & 7) * 8;
        #pragma unroll
        for (int c = 0; c < 6; ++c) {
            const int g = c >> 1, rh = c & 1;
            gload16(Xg + (size_t)rh * 32 * (3 * HH) + g * HH, L + g * 8192 + rh * 4096 + w * 1024);
        }
        const unsigned short* Hg = hb + (size_t)(rbase + (t >> 3)) * HH + bn * 64 + (t & 7) * 8;
        gload16(Hg,                   L + 24576 + w * 1024);
        gload16(Hg + (size_t)32 * HH, L + 24576 + 4096 + w * 1024);
        __syncthreads();

        unsigned short hv[4][4];
        #pragma unroll
        for (int r = 0; r < 4; ++r) {
            const int row = w * 16 + q * 4 + r;
            #pragma unroll
            for (int j = 0; j < 4; ++j) {
                const int col2 = (j * 16 + m) * 2;
                const float xr = __half2float(*(const __half*)(L + row * 128 + col2));
                const float xz = __half2float(*(const __half*)(L + 8192 + row * 128 + col2));
                const float xn = __half2float(*(const __half*)(L + 16384 + row * 128 + col2));
                const float ho = bf2f(*(const unsigned short*)(L + 24576 + row * 128 + col2));
                const float rg = sigf(xr + acc[half][0][j][r] + br[j]);
                const float zg = sigf(xz + acc[half][1][j][r] + bz[j]);
                const float ng = ftanh(xn + rg * (acc[half][2][j][r] + bnn[j]));
                hv[r][j] = f2bf((1.f - zg) * ng + zg * ho);
            }
        }
        __syncthreads();   // epilogue LDS reads done; reuse h_old area for h_out
        #pragma unroll
        for (int r = 0; r < 4; ++r) {
            const int row = w * 16 + q * 4 + r;
            #pragma unroll
            for (int j = 0; j < 4; ++j)
                *(unsigned short*)(L + 24576 + row * 128 + (j * 16 + m) * 2) = hv[r][j];
        }
        __syncthreads();
        // coalesced store: thread t -> row t>>2, 32B at col (t&3)*16
        {
            const int sr = t >> 2, sc = (t & 3) * 16;
            uint4 v0 = *(const uint4*)(L + 24576 + sr * 128 + sc * 2);
            uint4 v1 = *(const uint4*)(L + 24576 + sr * 128 + sc * 2 + 16);
            unsigned short* dst = hob + (size_t)(rbase + sr) * HH + bn * 64 + sc;
            *(uint4*)dst = v0;
            *(uint4*)(dst + 8) = v1;
        }
        __syncthreads();   // stores read L; next half's DMA overwrites it
    }
}

// ---------------------------------------------------------------------------
// Heads body (round-4 proven): 32 batch rows per block, BK=64 phase-1 staging.
// ---------------------------------------------------------------------------
__device__ __forceinline__ void heads_body(
    unsigned short* lds, const unsigned short* __restrict__ hxb,
    const unsigned short* __restrict__ w1c, const unsigned short* __restrict__ w2s,
    const unsigned short* __restrict__ w3s,
    const float* __restrict__ b1c, const float* __restrict__ b2c,
    const float* __restrict__ b3s,
    const float* __restrict__ cw3, const float* __restrict__ cb3,
    const int* __restrict__ actions,
    float* __restrict__ out_lp, float* __restrict__ out_ent,
    float* __restrict__ out_v, int tstep, int hblk, int t)
{
    char* sH = (char*)lds;              // 4 KB: two 2 KB kk-halves [32][64B]
    char* sW = (char*)lds + 4096;       // 16 KB: two 8 KB kk-halves [128][64B]
    unsigned short* u1 = lds;           // aliased after phase 1: [32][136]
    const int lane = t & 63, w = t >> 6;
    const int q = lane >> 4, m = lane & 15;
    const int row0 = hblk * 32;
    const int ri = (w & 1) * 16, ch = (w >> 1) * 64;

    // ---------------- phase 1: u1 = tanh(h @ w1c^T + b1c) ----------------
    f32x4v acc[4];
    #pragma unroll
    for (int j = 0; j < 4; ++j)
        #pragma unroll
        for (int r = 0; r < 4; ++r) acc[j][r] = 0.f;

    const unsigned short* Hrow = hxb + (size_t)(row0 + ((t >> 2) & 31)) * HH
                                 + (t >> 7) * 32 + (t & 3) * 8;
    const unsigned short* Wrow[4]; int WldsOff[4];
    #pragma unroll
    for (int c = 0; c < 4; ++c) {
        const int kk = c & 1, rb = (c >> 1) * 64;
        Wrow[c] = w1c + (size_t)(rb + (t >> 2)) * HH + kk * 32 + (t & 3) * 8;
        WldsOff[c] = kk * 8192 + rb * 64;
    }

    for (int ki = 0; ki < 8; ++ki) {
        const int k0 = ki * 64;
        gload16(Hrow + k0, sH + w * 1024);
        #pragma unroll
        for (int c = 0; c < 4; ++c)
            gload16(Wrow[c] + k0, sW + WldsOff[c] + w * 1024);
        __syncthreads();
        #pragma unroll
        for (int kk = 0; kk < 2; ++kk) {
            frag16 af = *(const frag16*)(sH + kk * 2048 + (ri + m) * 64 + q * 16);
            #pragma unroll
            for (int j = 0; j < 4; ++j) {
                frag16 bf = *(const frag16*)(sW + kk * 8192 + (ch + j * 16 + m) * 64 + q * 16);
                acc[j] = MFMA16(af, bf, acc[j]);
            }
        }
        __syncthreads();
    }
    #pragma unroll
    for (int j = 0; j < 4; ++j) {
        const int col = ch + j * 16 + m;
        const float bv = b1c[col];
        #pragma unroll
        for (int r = 0; r < 4; ++r)
            u1[(ri + q * 4 + r) * 136 + col] = f2bf(ftanh(acc[j][r] + bv));
    }
    __syncthreads();

    // ---------------- phase 2: u2 (actor ch=0 / critic ch=64) ----------------
    f32x4v acc2[4];
    #pragma unroll
    for (int j = 0; j < 4; ++j)
        #pragma unroll
        for (int r = 0; r < 4; ++r) acc2[j][r] = 0.f;
    #pragma unroll
    for (int kk = 0; kk < 2; ++kk) {
        frag16 af2 = *(const frag16*)(u1 + (ri + m) * 136 + ch + kk * 32 + q * 8);
        #pragma unroll
        for (int j = 0; j < 4; ++j) {
            frag16 bf2 = *(const frag16*)(w2s + (size_t)(ch + j * 16 + m) * 64 + kk * 32 + q * 8);
            acc2[j] = MFMA16(af2, bf2, acc2[j]);
        }
    }
    __syncthreads();
    #pragma unroll
    for (int j = 0; j < 4; ++j) {
        const int col = ch + j * 16 + m;
        const float bv = b2c[col];
        #pragma unroll
        for (int r = 0; r < 4; ++r)
            u1[(ri + q * 4 + r) * 136 + col] = f2bf(ftanh(acc2[j][r] + bv));
    }
    __syncthreads();

    // ---------------- phase 3 ----------------
    if (w < 2) {
        f32x4v acc3[13];
        #pragma unroll
        for (int j = 0; j < 13; ++j)
            #pragma unroll
            for (int r = 0; r < 4; ++r) acc3[j][r] = 0.f;
        #pragma unroll
        for (int kk = 0; kk < 2; ++kk) {
            frag16 af3 = *(const frag16*)(u1 + (w * 16 + m) * 136 + kk * 32 + q * 8);
            #pragma unroll
            for (int j = 0; j < 13; ++j) {
                frag16 bf3 = *(const frag16*)(w3s + (size_t)(j * 16 + m) * 64 + kk * 32 + q * 8);
                acc3[j] = MFMA16(af3, bf3, acc3[j]);
            }
        }
        float bcol[13];
        #pragma unroll
        for (int j = 0; j < 13; ++j) bcol[j] = b3s[j * 16 + m];
        const bool vlast = (m < 8);
        #pragma unroll
        for (int r = 0; r < 4; ++r) {
            const int gr = row0 + w * 16 + 4 * q + r;
            const int a = actions[(size_t)gr * TT + tstep];
            float lg[13], mx = -1e30f;
            #pragma unroll
            for (int j = 0; j < 13; ++j) {
                float v = acc3[j][r] + bcol[j];
                lg[j] = (j < 12 || vlast) ? v : -1e30f;
                mx = fmaxf(mx, lg[j]);
            }
            #pragma unroll
            for (int o = 1; o < 16; o <<= 1) mx = fmaxf(mx, __shfl_xor(mx, o));
            float s1 = 0.f, s2 = 0.f, sel = 0.f;
            #pragma unroll
            for (int j = 0; j < 13; ++j) {
                float e = __expf(lg[j] - mx);
                s1 += e; s2 += e * lg[j];
                sel += (j * 16 + m == a) ? lg[j] : 0.f;
            }
            #pragma unroll
            for (int o = 1; o < 16; o <<= 1) {
                s1 += __shfl_xor(s1, o); s2 += __shfl_xor(s2, o); sel += __shfl_xor(sel, o);
            }
            const float lse = mx + __logf(s1);
            if (m == 0) {
                out_lp[(size_t)gr * TT + tstep]  = sel - lse;
                out_ent[(size_t)gr * TT + tstep] = lse - s2 / s1;
            }
        }
    } else {
        const int row = (w - 2) * 16 + m;
        const unsigned short* u2row = u1 + row * 136 + 64 + q * 16;
        float pv = 0.f;
        #pragma unroll
        for (int kk = 0; kk < 16; ++kk)
            pv += bf2f(u2row[kk]) * cw3[q * 16 + kk];
        pv += __shfl_xor(pv, 16);
        pv += __shfl_xor(pv, 32);
        if (q == 0) out_v[(size_t)(row0 + row) * TT + tstep] = pv + cb3[0];
    }
}

// ---------------------------------------------------------------------------
// Fused per-step launch: blocks 0..1023 = gru_t ; blocks 1024..1535 = heads_{t-1}.
// gru block order: bm fast (bm = b & 127) so same-bn blocks share the W tile (L2).
// ---------------------------------------------------------------------------
__global__ __launch_bounds__(256, 4) void step_fused(
    const unsigned short* __restrict__ hin, unsigned short* __restrict__ hout,
    const unsigned short* __restrict__ whhb, const float* __restrict__ bhh,
    const __half* __restrict__ xg,
    const unsigned short* __restrict__ w1c, const unsigned short* __restrict__ w2s,
    const unsigned short* __restrict__ w3s,
    const float* __restrict__ b1c, const float* __restrict__ b2c,
    const float* __restrict__ b3s,
    const float* __restrict__ cw3, const float* __restrict__ cb3,
    const int* __restrict__ actions,
    float* __restrict__ out_lp, float* __restrict__ out_ent,
    float* __restrict__ out_v, int hstep)
{
    __shared__ unsigned short lds[16384];   // 32 KB -> 4 blocks/CU
    const int b = blockIdx.x;
    if (b < 1024) {
        gru_body(lds, hin, hout, whhb, bhh, xg, b & 127, b >> 7, threadIdx.x);
    } else if (hstep >= 0) {
        heads_body(lds, hin, w1c, w2s, w3s, b1c, b2c, b3s, cw3, cb3,
                   actions, out_lp, out_ent, out_v, hstep, b - 1024, threadIdx.x);
    }
}

__global__ __launch_bounds__(256) void heads_tail(
    const unsigned short* __restrict__ hx,
    const unsigned short* __restrict__ w1c, const unsigned short* __restrict__ w2s,
    const unsigned short* __restrict__ w3s,
    const float* __restrict__ b1c, const float* __restrict__ b2c,
    const float* __restrict__ b3s,
    const float* __restrict__ cw3, const float* __restrict__ cb3,
    const int* __restrict__ actions,
    float* __restrict__ out_lp, float* __restrict__ out_ent,
    float* __restrict__ out_v, int tstep)
{
    __shared__ unsigned short lds[10240];   // 20 KB
    heads_body(lds, hx, w1c, w2s, w3s, b1c, b2c, b3s, cw3, cb3,
               actions, out_lp, out_ent, out_v, tstep, blockIdx.x, threadIdx.x);
}

// ---------------------------------------------------------------------------
// One-time packing of head weights/biases.
// ---------------------------------------------------------------------------
__global__ void prep_heads(
    const float* __restrict__ aw1, const float* __restrict__ cw1,
    const float* __restrict__ aw2, const float* __restrict__ cw2,
    const float* __restrict__ aw3,
    const float* __restrict__ ab1, const float* __restrict__ cb1,
    const float* __restrict__ ab2, const float* __restrict__ cb2,
    const float* __restrict__ ab3,
    unsigned short* __restrict__ w1c, unsigned short* __restrict__ w2s,
    unsigned short* __restrict__ w3s,
    float* __restrict__ b1c, float* __restrict__ b2c, float* __restrict__ b3s)
{
    int i = blockIdx.x * 256 + threadIdx.x;
    if (i < 65536) { int r = i >> 9, c = i & 511;
        w1c[i] = f2bf(r < 64 ? aw1[r * 512 + c] : cw1[(r - 64) * 512 + c]); return; }
    i -= 65536;
    if (i < 8192) { int r = i >> 6, c = i & 63;
        w2s[i] = f2bf(r < 64 ? aw2[r * 64 + c] : cw2[(r - 64) * 64 + c]); return; }
    i -= 8192;
    if (i < 13312) { int r = i >> 6, c = i & 63;
        w3s[i] = f2bf(r < 200 ? aw3[r * 64 + c] : 0.f); return; }
    i -= 13312;
    if (i < 128) { b1c[i] = i < 64 ? ab1[i] : cb1[i - 64]; return; }
    i -= 128;
    if (i < 128) { b2c[i] = i < 64 ? ab2[i] : cb2[i - 64]; return; }
    i -= 128;
    if (i < 208) { b3s[i] = i < 200 ? ab3[i] : 0.f; return; }
}

__global__ void f2b_kernel(const float* __restrict__ s, unsigned short* __restrict__ d, int n) {
    int i = (blockIdx.x * 256 + threadIdx.x) * 4;
    if (i < n) {
        float4 v = *(const float4*)(s + i);
        ushort4 o;
        o.x = f2bf(v.x); o.y = f2bf(v.y); o.z = f2bf(v.z); o.w = f2bf(v.w);
        *(ushort4*)(d + i) = o;
    }
}

__global__ void copy_actions(const int* __restrict__ a, float* __restrict__ o, int n) {
    int i = blockIdx.x * 256 + threadIdx.x;
    if (i < n) o[i] = (float)a[i];
}

extern "C" void kernel_launch(void* const* d_in, const int* in_sizes, int n_in,
                              void* d_out, int out_size, void* d_ws, size_t ws_size,
                              hipStream_t stream)
{
    const float* images = (const float*)d_in[0];
    const int*   actions = (const int*)d_in[1];
    const float* enc_w1 = (const float*)d_in[2];
    const float* enc_b1 = (const float*)d_in[3];
    const float* enc_w2 = (const float*)d_in[4];
    const float* enc_b2 = (const float*)d_in[5];
    const float* gru_wih = (const float*)d_in[6];
    const float* gru_bih = (const float*)d_in[7];
    const float* gru_whh = (const float*)d_in[8];
    const float* gru_bhh = (const float*)d_in[9];
    const float* act_w1 = (const float*)d_in[10];
    const float* act_b1 = (const float*)d_in[11];
    const float* act_w2 = (const float*)d_in[12];
    const float* act_b2 = (const float*)d_in[13];
    const float* act_w3 = (const float*)d_in[14];
    const float* act_b3 = (const float*)d_in[15];
    const float* cri_w1 = (const float*)d_in[16];
    const float* cri_b1 = (const float*)d_in[17];
    const float* cri_w2 = (const float*)d_in[18];
    const float* cri_b2 = (const float*)d_in[19];
    const float* cri_w3 = (const float*)d_in[20];
    const float* cri_b3 = (const float*)d_in[21];

    char* ws = (char*)d_ws;
    unsigned short* imgb = (unsigned short*)ws;                    // 64MB, dead after enc1
    __half*         xg   = (__half*)ws;                            // 48MB, written by gemm3
    unsigned short* hbA  = (unsigned short*)(ws + 67108864);       // y1 / h ping (16MB)
    unsigned short* hbB  = (unsigned short*)(ws + 83886080);       // x  / h pong (16MB)
    unsigned short* w1b  = (unsigned short*)(ws + 100663296);
    unsigned short* w2b  = (unsigned short*)(ws + 102760448);
    unsigned short* wihb = (unsigned short*)(ws + 103284736);
    unsigned short* whhb = (unsigned short*)(ws + 104857600);
    unsigned short* w1c  = (unsigned short*)(ws + 106430464);      // [128,512]
    unsigned short* w2s  = (unsigned short*)(ws + 106561536);      // [128,64]
    unsigned short* w3s  = (unsigned short*)(ws + 106577920);      // [208,64]
    float*          b1c  = (float*)(ws + 106604544);
    float*          b2c  = (float*)(ws + 106605056);
    float*          b3s  = (float*)(ws + 106605568);

    float* out_act = (float*)d_out;
    float* out_lp  = out_act + (size_t)BB * TT;
    float* out_ent = out_lp  + (size_t)BB * TT;
    float* out_v   = out_ent + (size_t)BB * TT;

    dim3 blk(256);

    f2b_kernel<<<(BB * DIMG / 4 + 255) / 256, blk, 0, stream>>>(images, imgb, BB * DIMG);
    f2b_kernel<<<(512 * DIMG / 4 + 255) / 256, blk, 0, stream>>>(enc_w1, w1b, 512 * DIMG);
    f2b_kernel<<<(512 * 512 / 4 + 255) / 256, blk, 0, stream>>>(enc_w2, w2b, 512 * 512);
    f2b_kernel<<<(3 * HH * HH / 4 + 255) / 256, blk, 0, stream>>>(gru_wih, wihb, 3 * HH * HH);
    f2b_kernel<<<(3 * HH * HH / 4 + 255) / 256, blk, 0, stream>>>(gru_whh, whhb, 3 * HH * HH);
    prep_heads<<<(87504 + 255) / 256, blk, 0, stream>>>(
        act_w1, cri_w1, act_w2, cri_w2, act_w3,
        act_b1, cri_b1, act_b2, cri_b2, act_b3,
        w1c, w2s, w3s, b1c, b2c, b3s);

    // encoder + input-gate GEMMs; xg stored fp16
    gemm_bt_mfma<1, 1><<<dim3(BB / 128, 4), blk, 0, stream>>>(imgb, w1b, enc_b1, hbA, BB, 512, DIMG);
    gemm_bt_mfma<0, 1><<<dim3(BB / 128, 4), blk, 0, stream>>>(hbA, w2b, enc_b2, hbB, BB, 512, HH);
    gemm_bt_mfma<0, 2><<<dim3(BB / 128, 12), blk, 0, stream>>>(hbB, wihb, gru_bih, xg, BB, 1536, HH);

    // h0 = 0 in hbA (its y1 contents are dead after enc2)
    hipMemsetAsync(hbA, 0, (size_t)BB * HH * 2, stream);
    copy_actions<<<(BB * TT + 255) / 256, blk, 0, stream>>>(actions, out_act, BB * TT);

    for (int t = 0; t < TT; ++t) {
        const unsigned short* hin = (t & 1) ? hbB : hbA;
        unsigned short*      hout = (t & 1) ? hbA : hbB;
        step_fused<<<1536, blk, 0, stream>>>(hin, hout, whhb, gru_bhh, xg,
            w1c, w2s, w3s, b1c, b2c, b3s, cri_w3, cri_b3, actions,
            out_lp, out_ent, out_v, t - 1);
    }
    heads_tail<<<512, blk, 0, stream>>>((TT & 1) ? hbB : hbA, w1c, w2s, w3s,
        b1c, b2c, b3s, cri_w3, cri_b3, actions, out_lp, out_ent, out_v, TT - 1);
}

// Round 3
// 1539.601 us; speedup vs baseline: 1.0852x; 1.0852x over previous
//
#include <hip/hip_runtime.h>
#include <hip/hip_fp16.h>
#include <cstddef>
#include <cstdint>

#define BB 16384
#define DIMG 2048
#define HH 512
#define VOCAB 200
#define TT 20

using frag16 = __attribute__((ext_vector_type(8))) short;   // 8 x bf16 (4 VGPRs)
using f32x4v = __attribute__((ext_vector_type(4))) float;   // MFMA accumulator

#define MFMA16(a, b, c) __builtin_amdgcn_mfma_f32_16x16x32_bf16((a), (b), (c), 0, 0, 0)

__device__ __forceinline__ float bf2f(unsigned short u) {
    union { unsigned int i; float f; } c; c.i = ((unsigned int)u) << 16; return c.f;
}
__device__ __forceinline__ unsigned short f2bf(float f) {
    union { float f; unsigned int i; } c; c.f = f;
    unsigned int u = c.i;
    u = (u + 0x7FFFu + ((u >> 16) & 1u)) >> 16;   // RTNE
    return (unsigned short)u;
}
__device__ __forceinline__ float sigf(float x) { return 1.f / (1.f + __expf(-x)); }
__device__ __forceinline__ float ftanh(float x) {
    return 1.f - 2.f / (1.f + __expf(2.f * x));   // saturates correctly at +-inf
}
// async global->LDS, 16B/lane; LDS dest = wave-uniform base + lane*16
__device__ __forceinline__ void gload16(const void* g, void* l) {
    __builtin_amdgcn_global_load_lds(
        (__attribute__((address_space(1))) void*)g,
        (__attribute__((address_space(3))) void*)l, 16, 0, 0);
}

// ---------------------------------------------------------------------------
// bf16 MFMA GEMM for encoder: C = act(A[M,K] @ W[N,K]^T + bias).
// OM: 0=f32, 1=bf16, 2=f16 output.
// ---------------------------------------------------------------------------
template<int ACT, int OM>
__global__ __launch_bounds__(256) void gemm_bt_mfma(
    const unsigned short* __restrict__ A, const unsigned short* __restrict__ W,
    const float* __restrict__ bias, void* __restrict__ Cv, int M, int N, int K)
{
    __shared__ unsigned short As[128 * 32];
    __shared__ unsigned short Ws[128 * 32];
    const int t = threadIdx.x;
    const int lane = t & 63, w = t >> 6;
    const int bm = blockIdx.x, bn = blockIdx.y;
    const int wm = (w >> 1) * 64, wn = (w & 1) * 64;

    f32x4v acc[4][4];
    #pragma unroll
    for (int i = 0; i < 4; ++i)
        #pragma unroll
        for (int j = 0; j < 4; ++j)
            #pragma unroll
            for (int r = 0; r < 4; ++r) acc[i][j][r] = 0.f;

    const unsigned short* Ag  = A + (size_t)(bm * 128 + (t >> 2)) * K + (t & 3) * 8;
    const unsigned short* Ag2 = A + (size_t)(bm * 128 + 64 + (t >> 2)) * K + (t & 3) * 8;
    const unsigned short* Wg  = W + (size_t)(bn * 128 + (t >> 2)) * K + (t & 3) * 8;
    const unsigned short* Wg2 = W + (size_t)(bn * 128 + 64 + (t >> 2)) * K + (t & 3) * 8;
    char* AsB = (char*)As; char* WsB = (char*)Ws;

    const int kIters = K >> 5;
    for (int ki = 0; ki < kIters; ++ki) {
        const int k0 = ki * 32;
        gload16(Ag  + k0, AsB + w * 1024);
        gload16(Ag2 + k0, AsB + 4096 + w * 1024);
        gload16(Wg  + k0, WsB + w * 1024);
        gload16(Wg2 + k0, WsB + 4096 + w * 1024);
        __syncthreads();
        frag16 af[4], bf[4];
        #pragma unroll
        for (int i = 0; i < 4; ++i) {
            af[i] = *(const frag16*)(AsB + (wm + i * 16 + (lane & 15)) * 64 + (lane >> 4) * 16);
            bf[i] = *(const frag16*)(WsB + (wn + i * 16 + (lane & 15)) * 64 + (lane >> 4) * 16);
        }
        #pragma unroll
        for (int i = 0; i < 4; ++i)
            #pragma unroll
            for (int j = 0; j < 4; ++j)
                acc[i][j] = MFMA16(af[i], bf[j], acc[i][j]);
        __syncthreads();
    }

    #pragma unroll
    for (int j = 0; j < 4; ++j) {
        const int gn = bn * 128 + wn + j * 16 + (lane & 15);
        const float bv = bias[gn];
        #pragma unroll
        for (int i = 0; i < 4; ++i) {
            #pragma unroll
            for (int r = 0; r < 4; ++r) {
                const size_t gm = (size_t)(bm * 128 + wm + i * 16 + (lane >> 4) * 4 + r);
                float v = acc[i][j][r] + bv;
                if (ACT == 1) v = fmaxf(v, 0.f);
                if (OM == 0)      ((float*)Cv)[gm * N + gn] = v;
                else if (OM == 1) ((unsigned short*)Cv)[gm * N + gn] = f2bf(v);
                else              ((__half*)Cv)[gm * N + gn] = __float2half(v);
            }
        }
    }
}

// ---------------------------------------------------------------------------
// GRU step body, tile 128 rows x 64 h-cols (x3 gates), BK=64. 256 threads.
// A (h rows) loads DIRECTLY global->registers (16B frag16/lane, L2/L3-hot);
// A-loads are issued BEFORE the stage DMAs so (in-order vmcnt) the first
// MFMA waits at vmcnt(6), not a full drain.
// W (whh, 3 gates) is DOUBLE-BUFFERED in LDS (2 x 24KB): the stage for
// K-iter ki+1 is issued before computing ki, so the compiler's vmcnt(0)
// drain at the single per-iter barrier lands AFTER ~48 MFMAs of cover.
// LDS total 48KB (epilogue aliases first 32KB) -> 3 blocks/CU at (256,3),
// which round 1 proved spill-free for this accumulator footprint.
// ---------------------------------------------------------------------------
__device__ __forceinline__ void gru_body(
    unsigned short* lds,
    const unsigned short* __restrict__ hb, unsigned short* __restrict__ hob,
    const unsigned short* __restrict__ whhb, const float* __restrict__ bhh,
    const __half* __restrict__ xg, int bm, int bn, int t)
{
    char* L = (char*)lds;
    const int lane = t & 63, w = t >> 6;
    const int q = lane >> 4, m = lane & 15;

    f32x4v acc[2][3][4];
    #pragma unroll
    for (int i = 0; i < 2; ++i)
        #pragma unroll
        for (int g = 0; g < 3; ++g)
            #pragma unroll
            for (int j = 0; j < 4; ++j)
                #pragma unroll
                for (int r = 0; r < 4; ++r) acc[i][g][j][r] = 0.f;

    // ---- A-fragment direct global addresses (per-lane) ----
    const unsigned short* A0 = hb + (size_t)(bm * 128 + w * 16 + m) * HH + q * 8;
    const unsigned short* A1 = A0 + (size_t)64 * HH;

    // ---- W staging addresses (per-lane source for global_load_lds) ----
    const unsigned short* Wg0 = whhb + (size_t)(0 * HH + bn * 64 + (t >> 2)) * HH + (t & 3) * 8;
    const unsigned short* Wg1 = whhb + (size_t)(1 * HH + bn * 64 + (t >> 2)) * HH + (t & 3) * 8;
    const unsigned short* Wg2 = whhb + (size_t)(2 * HH + bn * 64 + (t >> 2)) * HH + (t & 3) * 8;

    // stage W K-tile (k0) into buffer b; layout [kk half 12KB][gate 4KB]
    auto STAGE = [&](int b, int k0) {
        char* Lb = L + b * 24576;
        gload16(Wg0 + k0,      Lb + w * 1024);
        gload16(Wg0 + k0 + 32, Lb + 12288 + w * 1024);
        gload16(Wg1 + k0,      Lb + 4096 + w * 1024);
        gload16(Wg1 + k0 + 32, Lb + 12288 + 4096 + w * 1024);
        gload16(Wg2 + k0,      Lb + 8192 + w * 1024);
        gload16(Wg2 + k0 + 32, Lb + 12288 + 8192 + w * 1024);
    };

    STAGE(0, 0);
    __syncthreads();

    for (int ki = 0; ki < 8; ++ki) {
        const int k0 = ki * 64;
        const int bsel = ki & 1;
        // A fragments for THIS iter, issued first (retire before stage loads)
        frag16 af[2][2];
        af[0][0] = *(const frag16*)(A0 + k0);
        af[0][1] = *(const frag16*)(A0 + k0 + 32);
        af[1][0] = *(const frag16*)(A1 + k0);
        af[1][1] = *(const frag16*)(A1 + k0 + 32);
        // prefetch next W tile into the other buffer
        if (ki < 7) STAGE(bsel ^ 1, k0 + 64);
        char* Lb = L + bsel * 24576;
        #pragma unroll
        for (int kk = 0; kk < 2; ++kk) {
            #pragma unroll
            for (int g = 0; g < 3; ++g)
                #pragma unroll
                for (int j = 0; j < 4; ++j) {
                    frag16 bf = *(const frag16*)(Lb + kk * 12288 + g * 4096 + (j * 16 + m) * 64 + q * 16);
                    acc[0][g][j] = MFMA16(af[0][kk], bf, acc[0][g][j]);
                    acc[1][g][j] = MFMA16(af[1][kk], bf, acc[1][g][j]);
                }
        }
        __syncthreads();   // drains next-tile stage (issued pre-compute) + flips
    }

    // biases: same columns for both row-halves -> hoist
    float br[4], bz[4], bnn[4];
    #pragma unroll
    for (int j = 0; j < 4; ++j) {
        const int gc = bn * 64 + j * 16 + m;
        br[j] = bhh[gc]; bz[j] = bhh[HH + gc]; bnn[j] = bhh[2 * HH + gc];
    }

    #pragma unroll
    for (int half = 0; half < 2; ++half) {
        const int rbase = bm * 128 + half * 64;
        // ---- epilogue DMA: xg tiles at L+g*8192, h_old at L+24576 ----
        const __half* Xg = xg + (size_t)(rbase + (t >> 3)) * (3 * HH) + bn * 64 + (t & 7) * 8;
        #pragma unroll
        for (int c = 0; c < 6; ++c) {
            const int g = c >> 1, rh = c & 1;
            gload16(Xg + (size_t)rh * 32 * (3 * HH) + g * HH, L + g * 8192 + rh * 4096 + w * 1024);
        }
        const unsigned short* Hg = hb + (size_t)(rbase + (t >> 3)) * HH + bn * 64 + (t & 7) * 8;
        gload16(Hg,                   L + 24576 + w * 1024);
        gload16(Hg + (size_t)32 * HH, L + 24576 + 4096 + w * 1024);
        __syncthreads();

        unsigned short hv[4][4];
        #pragma unroll
        for (int r = 0; r < 4; ++r) {
            const int row = w * 16 + q * 4 + r;
            #pragma unroll
            for (int j = 0; j < 4; ++j) {
                const int col2 = (j * 16 + m) * 2;
                const float xr = __half2float(*(const __half*)(L + row * 128 + col2));
                const float xz = __half2float(*(const __half*)(L + 8192 + row * 128 + col2));
                const float xn = __half2float(*(const __half*)(L + 16384 + row * 128 + col2));
                const float ho = bf2f(*(const unsigned short*)(L + 24576 + row * 128 + col2));
                const float rg = sigf(xr + acc[half][0][j][r] + br[j]);
                const float zg = sigf(xz + acc[half][1][j][r] + bz[j]);
                const float ng = ftanh(xn + rg * (acc[half][2][j][r] + bnn[j]));
                hv[r][j] = f2bf((1.f - zg) * ng + zg * ho);
            }
        }
        __syncthreads();   // epilogue LDS reads done; reuse h_old area for h_out
        #pragma unroll
        for (int r = 0; r < 4; ++r) {
            const int row = w * 16 + q * 4 + r;
            #pragma unroll
            for (int j = 0; j < 4; ++j)
                *(unsigned short*)(L + 24576 + row * 128 + (j * 16 + m) * 2) = hv[r][j];
        }
        __syncthreads();
        // coalesced store: thread t -> row t>>2, 32B at col (t&3)*16
        {
            const int sr = t >> 2, sc = (t & 3) * 16;
            uint4 v0 = *(const uint4*)(L + 24576 + sr * 128 + sc * 2);
            uint4 v1 = *(const uint4*)(L + 24576 + sr * 128 + sc * 2 + 16);
            unsigned short* dst = hob + (size_t)(rbase + sr) * HH + bn * 64 + sc;
            *(uint4*)dst = v0;
            *(uint4*)(dst + 8) = v1;
        }
        __syncthreads();   // stores read L; next half's DMA overwrites it
    }
}

// ---------------------------------------------------------------------------
// Heads body (round-4 proven): 32 batch rows per block, BK=64 phase-1 staging.
// ---------------------------------------------------------------------------
__device__ __forceinline__ void heads_body(
    unsigned short* lds, const unsigned short* __restrict__ hxb,
    const unsigned short* __restrict__ w1c, const unsigned short* __restrict__ w2s,
    const unsigned short* __restrict__ w3s,
    const float* __restrict__ b1c, const float* __restrict__ b2c,
    const float* __restrict__ b3s,
    const float* __restrict__ cw3, const float* __restrict__ cb3,
    const int* __restrict__ actions,
    float* __restrict__ out_lp, float* __restrict__ out_ent,
    float* __restrict__ out_v, int tstep, int hblk, int t)
{
    char* sH = (char*)lds;              // 4 KB: two 2 KB kk-halves [32][64B]
    char* sW = (char*)lds + 4096;       // 16 KB: two 8 KB kk-halves [128][64B]
    unsigned short* u1 = lds;           // aliased after phase 1: [32][136]
    const int lane = t & 63, w = t >> 6;
    const int q = lane >> 4, m = lane & 15;
    const int row0 = hblk * 32;
    const int ri = (w & 1) * 16, ch = (w >> 1) * 64;

    // ---------------- phase 1: u1 = tanh(h @ w1c^T + b1c) ----------------
    f32x4v acc[4];
    #pragma unroll
    for (int j = 0; j < 4; ++j)
        #pragma unroll
        for (int r = 0; r < 4; ++r) acc[j][r] = 0.f;

    const unsigned short* Hrow = hxb + (size_t)(row0 + ((t >> 2) & 31)) * HH
                                 + (t >> 7) * 32 + (t & 3) * 8;
    const unsigned short* Wrow[4]; int WldsOff[4];
    #pragma unroll
    for (int c = 0; c < 4; ++c) {
        const int kk = c & 1, rb = (c >> 1) * 64;
        Wrow[c] = w1c + (size_t)(rb + (t >> 2)) * HH + kk * 32 + (t & 3) * 8;
        WldsOff[c] = kk * 8192 + rb * 64;
    }

    for (int ki = 0; ki < 8; ++ki) {
        const int k0 = ki * 64;
        gload16(Hrow + k0, sH + w * 1024);
        #pragma unroll
        for (int c = 0; c < 4; ++c)
            gload16(Wrow[c] + k0, sW + WldsOff[c] + w * 1024);
        __syncthreads();
        #pragma unroll
        for (int kk = 0; kk < 2; ++kk) {
            frag16 af = *(const frag16*)(sH + kk * 2048 + (ri + m) * 64 + q * 16);
            #pragma unroll
            for (int j = 0; j < 4; ++j) {
                frag16 bf = *(const frag16*)(sW + kk * 8192 + (ch + j * 16 + m) * 64 + q * 16);
                acc[j] = MFMA16(af, bf, acc[j]);
            }
        }
        __syncthreads();
    }
    #pragma unroll
    for (int j = 0; j < 4; ++j) {
        const int col = ch + j * 16 + m;
        const float bv = b1c[col];
        #pragma unroll
        for (int r = 0; r < 4; ++r)
            u1[(ri + q * 4 + r) * 136 + col] = f2bf(ftanh(acc[j][r] + bv));
    }
    __syncthreads();

    // ---------------- phase 2: u2 (actor ch=0 / critic ch=64) ----------------
    f32x4v acc2[4];
    #pragma unroll
    for (int j = 0; j < 4; ++j)
        #pragma unroll
        for (int r = 0; r < 4; ++r) acc2[j][r] = 0.f;
    #pragma unroll
    for (int kk = 0; kk < 2; ++kk) {
        frag16 af2 = *(const frag16*)(u1 + (ri + m) * 136 + ch + kk * 32 + q * 8);
        #pragma unroll
        for (int j = 0; j < 4; ++j) {
            frag16 bf2 = *(const frag16*)(w2s + (size_t)(ch + j * 16 + m) * 64 + kk * 32 + q * 8);
            acc2[j] = MFMA16(af2, bf2, acc2[j]);
        }
    }
    __syncthreads();
    #pragma unroll
    for (int j = 0; j < 4; ++j) {
        const int col = ch + j * 16 + m;
        const float bv = b2c[col];
        #pragma unroll
        for (int r = 0; r < 4; ++r)
            u1[(ri + q * 4 + r) * 136 + col] = f2bf(ftanh(acc2[j][r] + bv));
    }
    __syncthreads();

    // ---------------- phase 3 ----------------
    if (w < 2) {
        f32x4v acc3[13];
        #pragma unroll
        for (int j = 0; j < 13; ++j)
            #pragma unroll
            for (int r = 0; r < 4; ++r) acc3[j][r] = 0.f;
        #pragma unroll
        for (int kk = 0; kk < 2; ++kk) {
            frag16 af3 = *(const frag16*)(u1 + (w * 16 + m) * 136 + kk * 32 + q * 8);
            #pragma unroll
            for (int j = 0; j < 13; ++j) {
                frag16 bf3 = *(const frag16*)(w3s + (size_t)(j * 16 + m) * 64 + kk * 32 + q * 8);
                acc3[j] = MFMA16(af3, bf3, acc3[j]);
            }
        }
        float bcol[13];
        #pragma unroll
        for (int j = 0; j < 13; ++j) bcol[j] = b3s[j * 16 + m];
        const bool vlast = (m < 8);
        #pragma unroll
        for (int r = 0; r < 4; ++r) {
            const int gr = row0 + w * 16 + 4 * q + r;
            const int a = actions[(size_t)gr * TT + tstep];
            float lg[13], mx = -1e30f;
            #pragma unroll
            for (int j = 0; j < 13; ++j) {
                float v = acc3[j][r] + bcol[j];
                lg[j] = (j < 12 || vlast) ? v : -1e30f;
                mx = fmaxf(mx, lg[j]);
            }
            #pragma unroll
            for (int o = 1; o < 16; o <<= 1) mx = fmaxf(mx, __shfl_xor(mx, o));
            float s1 = 0.f, s2 = 0.f, sel = 0.f;
            #pragma unroll
            for (int j = 0; j < 13; ++j) {
                float e = __expf(lg[j] - mx);
                s1 += e; s2 += e * lg[j];
                sel += (j * 16 + m == a) ? lg[j] : 0.f;
            }
            #pragma unroll
            for (int o = 1; o < 16; o <<= 1) {
                s1 += __shfl_xor(s1, o); s2 += __shfl_xor(s2, o); sel += __shfl_xor(sel, o);
            }
            const float lse = mx + __logf(s1);
            if (m == 0) {
                out_lp[(size_t)gr * TT + tstep]  = sel - lse;
                out_ent[(size_t)gr * TT + tstep] = lse - s2 / s1;
            }
        }
    } else {
        const int row = (w - 2) * 16 + m;
        const unsigned short* u2row = u1 + row * 136 + 64 + q * 16;
        float pv = 0.f;
        #pragma unroll
        for (int kk = 0; kk < 16; ++kk)
            pv += bf2f(u2row[kk]) * cw3[q * 16 + kk];
        pv += __shfl_xor(pv, 16);
        pv += __shfl_xor(pv, 32);
        if (q == 0) out_v[(size_t)(row0 + row) * TT + tstep] = pv + cb3[0];
    }
}

// ---------------------------------------------------------------------------
// Fused per-step launch: blocks 0..1023 = gru_t ; blocks 1024..1535 = heads_{t-1}.
// gru block order: bm fast (bm = b & 127) so same-bn blocks share the W tile (L2).
// ---------------------------------------------------------------------------
__global__ __launch_bounds__(256, 3) void step_fused(
    const unsigned short* __restrict__ hin, unsigned short* __restrict__ hout,
    const unsigned short* __restrict__ whhb, const float* __restrict__ bhh,
    const __half* __restrict__ xg,
    const unsigned short* __restrict__ w1c, const unsigned short* __restrict__ w2s,
    const unsigned short* __restrict__ w3s,
    const float* __restrict__ b1c, const float* __restrict__ b2c,
    const float* __restrict__ b3s,
    const float* __restrict__ cw3, const float* __restrict__ cb3,
    const int* __restrict__ actions,
    float* __restrict__ out_lp, float* __restrict__ out_ent,
    float* __restrict__ out_v, int hstep)
{
    __shared__ unsigned short lds[24576];   // 48 KB -> 3 blocks/CU
    const int b = blockIdx.x;
    if (b < 1024) {
        gru_body(lds, hin, hout, whhb, bhh, xg, b & 127, b >> 7, threadIdx.x);
    } else if (hstep >= 0) {
        heads_body(lds, hin, w1c, w2s, w3s, b1c, b2c, b3s, cw3, cb3,
                   actions, out_lp, out_ent, out_v, hstep, b - 1024, threadIdx.x);
    }
}

__global__ __launch_bounds__(256) void heads_tail(
    const unsigned short* __restrict__ hx,
    const unsigned short* __restrict__ w1c, const unsigned short* __restrict__ w2s,
    const unsigned short* __restrict__ w3s,
    const float* __restrict__ b1c, const float* __restrict__ b2c,
    const float* __restrict__ b3s,
    const float* __restrict__ cw3, const float* __restrict__ cb3,
    const int* __restrict__ actions,
    float* __restrict__ out_lp, float* __restrict__ out_ent,
    float* __restrict__ out_v, int tstep)
{
    __shared__ unsigned short lds[10240];   // 20 KB
    heads_body(lds, hx, w1c, w2s, w3s, b1c, b2c, b3s, cw3, cb3,
               actions, out_lp, out_ent, out_v, tstep, blockIdx.x, threadIdx.x);
}

// ---------------------------------------------------------------------------
// One-time packing of head weights/biases.
// ---------------------------------------------------------------------------
__global__ void prep_heads(
    const float* __restrict__ aw1, const float* __restrict__ cw1,
    const float* __restrict__ aw2, const float* __restrict__ cw2,
    const float* __restrict__ aw3,
    const float* __restrict__ ab1, const float* __restrict__ cb1,
    const float* __restrict__ ab2, const float* __restrict__ cb2,
    const float* __restrict__ ab3,
    unsigned short* __restrict__ w1c, unsigned short* __restrict__ w2s,
    unsigned short* __restrict__ w3s,
    float* __restrict__ b1c, float* __restrict__ b2c, float* __restrict__ b3s)
{
    int i = blockIdx.x * 256 + threadIdx.x;
    if (i < 65536) { int r = i >> 9, c = i & 511;
        w1c[i] = f2bf(r < 64 ? aw1[r * 512 + c] : cw1[(r - 64) * 512 + c]); return; }
    i -= 65536;
    if (i < 8192) { int r = i >> 6, c = i & 63;
        w2s[i] = f2bf(r < 64 ? aw2[r * 64 + c] : cw2[(r - 64) * 64 + c]); return; }
    i -= 8192;
    if (i < 13312) { int r = i >> 6, c = i & 63;
        w3s[i] = f2bf(r < 200 ? aw3[r * 64 + c] : 0.f); return; }
    i -= 13312;
    if (i < 128) { b1c[i] = i < 64 ? ab1[i] : cb1[i - 64]; return; }
    i -= 128;
    if (i < 128) { b2c[i] = i < 64 ? ab2[i] : cb2[i - 64]; return; }
    i -= 128;
    if (i < 208) { b3s[i] = i < 200 ? ab3[i] : 0.f; return; }
}

__global__ void f2b_kernel(const float* __restrict__ s, unsigned short* __restrict__ d, int n) {
    int i = (blockIdx.x * 256 + threadIdx.x) * 4;
    if (i < n) {
        float4 v = *(const float4*)(s + i);
        ushort4 o;
        o.x = f2bf(v.x); o.y = f2bf(v.y); o.z = f2bf(v.z); o.w = f2bf(v.w);
        *(ushort4*)(d + i) = o;
    }
}

__global__ void copy_actions(const int* __restrict__ a, float* __restrict__ o, int n) {
    int i = blockIdx.x * 256 + threadIdx.x;
    if (i < n) o[i] = (float)a[i];
}

extern "C" void kernel_launch(void* const* d_in, const int* in_sizes, int n_in,
                              void* d_out, int out_size, void* d_ws, size_t ws_size,
                              hipStream_t stream)
{
    const float* images = (const float*)d_in[0];
    const int*   actions = (const int*)d_in[1];
    const float* enc_w1 = (const float*)d_in[2];
    const float* enc_b1 = (const float*)d_in[3];
    const float* enc_w2 = (const float*)d_in[4];
    const float* enc_b2 = (const float*)d_in[5];
    const float* gru_wih = (const float*)d_in[6];
    const float* gru_bih = (const float*)d_in[7];
    const float* gru_whh = (const float*)d_in[8];
    const float* gru_bhh = (const float*)d_in[9];
    const float* act_w1 = (const float*)d_in[10];
    const float* act_b1 = (const float*)d_in[11];
    const float* act_w2 = (const float*)d_in[12];
    const float* act_b2 = (const float*)d_in[13];
    const float* act_w3 = (const float*)d_in[14];
    const float* act_b3 = (const float*)d_in[15];
    const float* cri_w1 = (const float*)d_in[16];
    const float* cri_b1 = (const float*)d_in[17];
    const float* cri_w2 = (const float*)d_in[18];
    const float* cri_b2 = (const float*)d_in[19];
    const float* cri_w3 = (const float*)d_in[20];
    const float* cri_b3 = (const float*)d_in[21];

    char* ws = (char*)d_ws;
    unsigned short* imgb = (unsigned short*)ws;                    // 64MB, dead after enc1
    __half*         xg   = (__half*)ws;                            // 48MB, written by gemm3
    unsigned short* hbA  = (unsigned short*)(ws + 67108864);       // y1 / h ping (16MB)
    unsigned short* hbB  = (unsigned short*)(ws + 83886080);       // x  / h pong (16MB)
    unsigned short* w1b  = (unsigned short*)(ws + 100663296);
    unsigned short* w2b  = (unsigned short*)(ws + 102760448);
    unsigned short* wihb = (unsigned short*)(ws + 103284736);
    unsigned short* whhb = (unsigned short*)(ws + 104857600);
    unsigned short* w1c  = (unsigned short*)(ws + 106430464);      // [128,512]
    unsigned short* w2s  = (unsigned short*)(ws + 106561536);      // [128,64]
    unsigned short* w3s  = (unsigned short*)(ws + 106577920);      // [208,64]
    float*          b1c  = (float*)(ws + 106604544);
    float*          b2c  = (float*)(ws + 106605056);
    float*          b3s  = (float*)(ws + 106605568);

    float* out_act = (float*)d_out;
    float* out_lp  = out_act + (size_t)BB * TT;
    float* out_ent = out_lp  + (size_t)BB * TT;
    float* out_v   = out_ent + (size_t)BB * TT;

    dim3 blk(256);

    f2b_kernel<<<(BB * DIMG / 4 + 255) / 256, blk, 0, stream>>>(images, imgb, BB * DIMG);
    f2b_kernel<<<(512 * DIMG / 4 + 255) / 256, blk, 0, stream>>>(enc_w1, w1b, 512 * DIMG);
    f2b_kernel<<<(512 * 512 / 4 + 255) / 256, blk, 0, stream>>>(enc_w2, w2b, 512 * 512);
    f2b_kernel<<<(3 * HH * HH / 4 + 255) / 256, blk, 0, stream>>>(gru_wih, wihb, 3 * HH * HH);
    f2b_kernel<<<(3 * HH * HH / 4 + 255) / 256, blk, 0, stream>>>(gru_whh, whhb, 3 * HH * HH);
    prep_heads<<<(87504 + 255) / 256, blk, 0, stream>>>(
        act_w1, cri_w1, act_w2, cri_w2, act_w3,
        act_b1, cri_b1, act_b2, cri_b2, act_b3,
        w1c, w2s, w3s, b1c, b2c, b3s);

    // encoder + input-gate GEMMs; xg stored fp16
    gemm_bt_mfma<1, 1><<<dim3(BB / 128, 4), blk, 0, stream>>>(imgb, w1b, enc_b1, hbA, BB, 512, DIMG);
    gemm_bt_mfma<0, 1><<<dim3(BB / 128, 4), blk, 0, stream>>>(hbA, w2b, enc_b2, hbB, BB, 512, HH);
    gemm_bt_mfma<0, 2><<<dim3(BB / 128, 12), blk, 0, stream>>>(hbB, wihb, gru_bih, xg, BB, 1536, HH);

    // h0 = 0 in hbA (its y1 contents are dead after enc2)
    hipMemsetAsync(hbA, 0, (size_t)BB * HH * 2, stream);
    copy_actions<<<(BB * TT + 255) / 256, blk, 0, stream>>>(actions, out_act, BB * TT);

    for (int t = 0; t < TT; ++t) {
        const unsigned short* hin = (t & 1) ? hbB : hbA;
        unsigned short*      hout = (t & 1) ? hbA : hbB;
        step_fused<<<1536, blk, 0, stream>>>(hin, hout, whhb, gru_bhh, xg,
            w1c, w2s, w3s, b1c, b2c, b3s, cri_w3, cri_b3, actions,
            out_lp, out_ent, out_v, t - 1);
    }
    heads_tail<<<512, blk, 0, stream>>>((TT & 1) ? hbB : hbA, w1c, w2s, w3s,
        b1c, b2c, b3s, cri_w3, cri_b3, actions, out_lp, out_ent, out_v, TT - 1);
}

// Round 4
// 1484.933 us; speedup vs baseline: 1.1252x; 1.0368x over previous
//
#include <hip/hip_runtime.h>
#include <hip/hip_fp16.h>
#include <cstddef>
#include <cstdint>

#define BB 16384
#define DIMG 2048
#define HH 512
#define VOCAB 200
#define TT 20

using frag16 = __attribute__((ext_vector_type(8))) short;   // 8 x bf16 (4 VGPRs)
using f32x4v = __attribute__((ext_vector_type(4))) float;   // MFMA accumulator

#define MFMA16(a, b, c) __builtin_amdgcn_mfma_f32_16x16x32_bf16((a), (b), (c), 0, 0, 0)

__device__ __forceinline__ float bf2f(unsigned short u) {
    union { unsigned int i; float f; } c; c.i = ((unsigned int)u) << 16; return c.f;
}
__device__ __forceinline__ unsigned short f2bf(float f) {
    union { float f; unsigned int i; } c; c.f = f;
    unsigned int u = c.i;
    u = (u + 0x7FFFu + ((u >> 16) & 1u)) >> 16;   // RTNE
    return (unsigned short)u;
}
__device__ __forceinline__ float sigf(float x) { return 1.f / (1.f + __expf(-x)); }
__device__ __forceinline__ float ftanh(float x) {
    return 1.f - 2.f / (1.f + __expf(2.f * x));   // saturates correctly at +-inf
}
// async global->LDS, 16B/lane; LDS dest = wave-uniform base + lane*16
__device__ __forceinline__ void gload16(const void* g, void* l) {
    __builtin_amdgcn_global_load_lds(
        (__attribute__((address_space(1))) void*)g,
        (__attribute__((address_space(3))) void*)l, 16, 0, 0);
}

// ---------------------------------------------------------------------------
// LDS bank-conflict swizzle (T2, rule 21: both-sides-or-neither).
// [64-row][64B] tiles staged via global_load_lds are read as per-row 16B
// frags at (row*64 + q*16): bank = (m*16+q*4)&31 -> 8-way conflict.
// Involution: 16B chunk index ^= (row>>1)&3.
//   stage side: global source chunk (t&3) -> (t&3)^((t>>3)&3)  (LDS linear)
//   read  side: q -> q^((m>>1)&3)  (row-base bits >=8 never touch the XOR)
// Post-swizzle: each q-group covers 8 bank-quads -> 2-way aliasing = free.
// ---------------------------------------------------------------------------

// ---------------------------------------------------------------------------
// bf16 MFMA GEMM for encoder: C = act(A[M,K] @ W[N,K]^T + bias).
// OM: 0=f32, 1=bf16, 2=f16 output.
// ---------------------------------------------------------------------------
template<int ACT, int OM>
__global__ __launch_bounds__(256) void gemm_bt_mfma(
    const unsigned short* __restrict__ A, const unsigned short* __restrict__ W,
    const float* __restrict__ bias, void* __restrict__ Cv, int M, int N, int K)
{
    __shared__ unsigned short As[128 * 32];
    __shared__ unsigned short Ws[128 * 32];
    const int t = threadIdx.x;
    const int lane = t & 63, w = t >> 6;
    const int bm = blockIdx.x, bn = blockIdx.y;
    const int wm = (w >> 1) * 64, wn = (w & 1) * 64;

    f32x4v acc[4][4];
    #pragma unroll
    for (int i = 0; i < 4; ++i)
        #pragma unroll
        for (int j = 0; j < 4; ++j)
            #pragma unroll
            for (int r = 0; r < 4; ++r) acc[i][j][r] = 0.f;

    const unsigned short* Ag  = A + (size_t)(bm * 128 + (t >> 2)) * K + (t & 3) * 8;
    const unsigned short* Ag2 = A + (size_t)(bm * 128 + 64 + (t >> 2)) * K + (t & 3) * 8;
    const unsigned short* Wg  = W + (size_t)(bn * 128 + (t >> 2)) * K + (t & 3) * 8;
    const unsigned short* Wg2 = W + (size_t)(bn * 128 + 64 + (t >> 2)) * K + (t & 3) * 8;
    char* AsB = (char*)As; char* WsB = (char*)Ws;

    const int kIters = K >> 5;
    for (int ki = 0; ki < kIters; ++ki) {
        const int k0 = ki * 32;
        gload16(Ag  + k0, AsB + w * 1024);
        gload16(Ag2 + k0, AsB + 4096 + w * 1024);
        gload16(Wg  + k0, WsB + w * 1024);
        gload16(Wg2 + k0, WsB + 4096 + w * 1024);
        __syncthreads();
        frag16 af[4], bf[4];
        #pragma unroll
        for (int i = 0; i < 4; ++i) {
            af[i] = *(const frag16*)(AsB + (wm + i * 16 + (lane & 15)) * 64 + (lane >> 4) * 16);
            bf[i] = *(const frag16*)(WsB + (wn + i * 16 + (lane & 15)) * 64 + (lane >> 4) * 16);
        }
        #pragma unroll
        for (int i = 0; i < 4; ++i)
            #pragma unroll
            for (int j = 0; j < 4; ++j)
                acc[i][j] = MFMA16(af[i], bf[j], acc[i][j]);
        __syncthreads();
    }

    #pragma unroll
    for (int j = 0; j < 4; ++j) {
        const int gn = bn * 128 + wn + j * 16 + (lane & 15);
        const float bv = bias[gn];
        #pragma unroll
        for (int i = 0; i < 4; ++i) {
            #pragma unroll
            for (int r = 0; r < 4; ++r) {
                const size_t gm = (size_t)(bm * 128 + wm + i * 16 + (lane >> 4) * 4 + r);
                float v = acc[i][j][r] + bv;
                if (ACT == 1) v = fmaxf(v, 0.f);
                if (OM == 0)      ((float*)Cv)[gm * N + gn] = v;
                else if (OM == 1) ((unsigned short*)Cv)[gm * N + gn] = f2bf(v);
                else              ((__half*)Cv)[gm * N + gn] = __float2half(v);
            }
        }
    }
}

// ---------------------------------------------------------------------------
// GRU step body, tile 128 rows x 64 h-cols (x3 gates), BK=64. 256 threads.
// A (h rows) loads DIRECTLY global->registers (16B frag16/lane, L2/L3-hot).
// W (whh, 3 gates) double-buffered in LDS (2 x 24KB), XOR-swizzled (see top)
// so the per-row 16B frag reads are bank-conflict-free.
// LDS total 48KB (epilogue aliases first 32KB) -> 3 blocks/CU at (256,3).
// ---------------------------------------------------------------------------
__device__ __forceinline__ void gru_body(
    unsigned short* lds,
    const unsigned short* __restrict__ hb, unsigned short* __restrict__ hob,
    const unsigned short* __restrict__ whhb, const float* __restrict__ bhh,
    const __half* __restrict__ xg, int bm, int bn, int t)
{
    char* L = (char*)lds;
    const int lane = t & 63, w = t >> 6;
    const int q = lane >> 4, m = lane & 15;
    const int qs = q ^ ((m >> 1) & 3);                    // swizzled read chunk
    const int scol = ((t & 3) ^ ((t >> 3) & 3)) * 8;      // swizzled stage chunk (elems)

    f32x4v acc[2][3][4];
    #pragma unroll
    for (int i = 0; i < 2; ++i)
        #pragma unroll
        for (int g = 0; g < 3; ++g)
            #pragma unroll
            for (int j = 0; j < 4; ++j)
                #pragma unroll
                for (int r = 0; r < 4; ++r) acc[i][g][j][r] = 0.f;

    // ---- A-fragment direct global addresses (per-lane) ----
    const unsigned short* A0 = hb + (size_t)(bm * 128 + w * 16 + m) * HH + q * 8;
    const unsigned short* A1 = A0 + (size_t)64 * HH;

    // ---- W staging addresses (per-lane source, chunk pre-swizzled) ----
    const unsigned short* Wg0 = whhb + (size_t)(0 * HH + bn * 64 + (t >> 2)) * HH + scol;
    const unsigned short* Wg1 = whhb + (size_t)(1 * HH + bn * 64 + (t >> 2)) * HH + scol;
    const unsigned short* Wg2 = whhb + (size_t)(2 * HH + bn * 64 + (t >> 2)) * HH + scol;

    // stage W K-tile (k0) into buffer b; layout [kk half 12KB][gate 4KB]
    auto STAGE = [&](int b, int k0) {
        char* Lb = L + b * 24576;
        gload16(Wg0 + k0,      Lb + w * 1024);
        gload16(Wg0 + k0 + 32, Lb + 12288 + w * 1024);
        gload16(Wg1 + k0,      Lb + 4096 + w * 1024);
        gload16(Wg1 + k0 + 32, Lb + 12288 + 4096 + w * 1024);
        gload16(Wg2 + k0,      Lb + 8192 + w * 1024);
        gload16(Wg2 + k0 + 32, Lb + 12288 + 8192 + w * 1024);
    };

    STAGE(0, 0);
    __syncthreads();

    for (int ki = 0; ki < 8; ++ki) {
        const int k0 = ki * 64;
        const int bsel = ki & 1;
        // A fragments for THIS iter, issued first (retire before stage loads)
        frag16 af[2][2];
        af[0][0] = *(const frag16*)(A0 + k0);
        af[0][1] = *(const frag16*)(A0 + k0 + 32);
        af[1][0] = *(const frag16*)(A1 + k0);
        af[1][1] = *(const frag16*)(A1 + k0 + 32);
        // prefetch next W tile into the other buffer
        if (ki < 7) STAGE(bsel ^ 1, k0 + 64);
        char* Lb = L + bsel * 24576;
        #pragma unroll
        for (int kk = 0; kk < 2; ++kk) {
            #pragma unroll
            for (int g = 0; g < 3; ++g)
                #pragma unroll
                for (int j = 0; j < 4; ++j) {
                    frag16 bf = *(const frag16*)(Lb + kk * 12288 + g * 4096 + (j * 16 + m) * 64 + qs * 16);
                    acc[0][g][j] = MFMA16(af[0][kk], bf, acc[0][g][j]);
                    acc[1][g][j] = MFMA16(af[1][kk], bf, acc[1][g][j]);
                }
        }
        __syncthreads();   // drains next-tile stage (issued pre-compute) + flips
    }

    // biases: same columns for both row-halves -> hoist
    float br[4], bz[4], bnn[4];
    #pragma unroll
    for (int j = 0; j < 4; ++j) {
        const int gc = bn * 64 + j * 16 + m;
        br[j] = bhh[gc]; bz[j] = bhh[HH + gc]; bnn[j] = bhh[2 * HH + gc];
    }

    #pragma unroll
    for (int half = 0; half < 2; ++half) {
        const int rbase = bm * 128 + half * 64;
        // ---- epilogue DMA: xg tiles at L+g*8192, h_old at L+24576 ----
        const __half* Xg = xg + (size_t)(rbase + (t >> 3)) * (3 * HH) + bn * 64 + (t & 7) * 8;
        #pragma unroll
        for (int c = 0; c < 6; ++c) {
            const int g = c >> 1, rh = c & 1;
            gload16(Xg + (size_t)rh * 32 * (3 * HH) + g * HH, L + g * 8192 + rh * 4096 + w * 1024);
        }
        const unsigned short* Hg = hb + (size_t)(rbase + (t >> 3)) * HH + bn * 64 + (t & 7) * 8;
        gload16(Hg,                   L + 24576 + w * 1024);
        gload16(Hg + (size_t)32 * HH, L + 24576 + 4096 + w * 1024);
        __syncthreads();

        unsigned short hv[4][4];
        #pragma unroll
        for (int r = 0; r < 4; ++r) {
            const int row = w * 16 + q * 4 + r;
            #pragma unroll
            for (int j = 0; j < 4; ++j) {
                const int col2 = (j * 16 + m) * 2;
                const float xr = __half2float(*(const __half*)(L + row * 128 + col2));
                const float xz = __half2float(*(const __half*)(L + 8192 + row * 128 + col2));
                const float xn = __half2float(*(const __half*)(L + 16384 + row * 128 + col2));
                const float ho = bf2f(*(const unsigned short*)(L + 24576 + row * 128 + col2));
                const float rg = sigf(xr + acc[half][0][j][r] + br[j]);
                const float zg = sigf(xz + acc[half][1][j][r] + bz[j]);
                const float ng = ftanh(xn + rg * (acc[half][2][j][r] + bnn[j]));
                hv[r][j] = f2bf((1.f - zg) * ng + zg * ho);
            }
        }
        __syncthreads();   // epilogue LDS reads done; reuse h_old area for h_out
        #pragma unroll
        for (int r = 0; r < 4; ++r) {
            const int row = w * 16 + q * 4 + r;
            #pragma unroll
            for (int j = 0; j < 4; ++j)
                *(unsigned short*)(L + 24576 + row * 128 + (j * 16 + m) * 2) = hv[r][j];
        }
        __syncthreads();
        // coalesced store: thread t -> row t>>2, 32B at col (t&3)*16
        {
            const int sr = t >> 2, sc = (t & 3) * 16;
            uint4 v0 = *(const uint4*)(L + 24576 + sr * 128 + sc * 2);
            uint4 v1 = *(const uint4*)(L + 24576 + sr * 128 + sc * 2 + 16);
            unsigned short* dst = hob + (size_t)(rbase + sr) * HH + bn * 64 + sc;
            *(uint4*)dst = v0;
            *(uint4*)(dst + 8) = v1;
        }
        __syncthreads();   // stores read L; next half's DMA overwrites it
    }
}

// ---------------------------------------------------------------------------
// Heads body: 32 batch rows per block, BK=64 phase-1 staging.
// Phase-1 sH/sW tiles use the same XOR swizzle (stage + read sides).
// ---------------------------------------------------------------------------
__device__ __forceinline__ void heads_body(
    unsigned short* lds, const unsigned short* __restrict__ hxb,
    const unsigned short* __restrict__ w1c, const unsigned short* __restrict__ w2s,
    const unsigned short* __restrict__ w3s,
    const float* __restrict__ b1c, const float* __restrict__ b2c,
    const float* __restrict__ b3s,
    const float* __restrict__ cw3, const float* __restrict__ cb3,
    const int* __restrict__ actions,
    float* __restrict__ out_lp, float* __restrict__ out_ent,
    float* __restrict__ out_v, int tstep, int hblk, int t)
{
    char* sH = (char*)lds;              // 4 KB: two 2 KB kk-halves [32][64B]
    char* sW = (char*)lds + 4096;       // 16 KB: two 8 KB kk-halves [128][64B]
    unsigned short* u1 = lds;           // aliased after phase 1: [32][136]
    const int lane = t & 63, w = t >> 6;
    const int q = lane >> 4, m = lane & 15;
    const int qs = q ^ ((m >> 1) & 3);                    // swizzled read chunk
    const int scol = ((t & 3) ^ ((t >> 3) & 3)) * 8;      // swizzled stage chunk
    const int row0 = hblk * 32;
    const int ri = (w & 1) * 16, ch = (w >> 1) * 64;

    // ---------------- phase 1: u1 = tanh(h @ w1c^T + b1c) ----------------
    f32x4v acc[4];
    #pragma unroll
    for (int j = 0; j < 4; ++j)
        #pragma unroll
        for (int r = 0; r < 4; ++r) acc[j][r] = 0.f;

    const unsigned short* Hrow = hxb + (size_t)(row0 + ((t >> 2) & 31)) * HH
                                 + (t >> 7) * 32 + scol;
    const unsigned short* Wrow[4]; int WldsOff[4];
    #pragma unroll
    for (int c = 0; c < 4; ++c) {
        const int kk = c & 1, rb = (c >> 1) * 64;
        Wrow[c] = w1c + (size_t)(rb + (t >> 2)) * HH + kk * 32 + scol;
        WldsOff[c] = kk * 8192 + rb * 64;
    }

    for (int ki = 0; ki < 8; ++ki) {
        const int k0 = ki * 64;
        gload16(Hrow + k0, sH + w * 1024);
        #pragma unroll
        for (int c = 0; c < 4; ++c)
            gload16(Wrow[c] + k0, sW + WldsOff[c] + w * 1024);
        __syncthreads();
        #pragma unroll
        for (int kk = 0; kk < 2; ++kk) {
            frag16 af = *(const frag16*)(sH + kk * 2048 + (ri + m) * 64 + qs * 16);
            #pragma unroll
            for (int j = 0; j < 4; ++j) {
                frag16 bf = *(const frag16*)(sW + kk * 8192 + (ch + j * 16 + m) * 64 + qs * 16);
                acc[j] = MFMA16(af, bf, acc[j]);
            }
        }
        __syncthreads();
    }
    #pragma unroll
    for (int j = 0; j < 4; ++j) {
        const int col = ch + j * 16 + m;
        const float bv = b1c[col];
        #pragma unroll
        for (int r = 0; r < 4; ++r)
            u1[(ri + q * 4 + r) * 136 + col] = f2bf(ftanh(acc[j][r] + bv));
    }
    __syncthreads();

    // ---------------- phase 2: u2 (actor ch=0 / critic ch=64) ----------------
    f32x4v acc2[4];
    #pragma unroll
    for (int j = 0; j < 4; ++j)
        #pragma unroll
        for (int r = 0; r < 4; ++r) acc2[j][r] = 0.f;
    #pragma unroll
    for (int kk = 0; kk < 2; ++kk) {
        frag16 af2 = *(const frag16*)(u1 + (ri + m) * 136 + ch + kk * 32 + q * 8);
        #pragma unroll
        for (int j = 0; j < 4; ++j) {
            frag16 bf2 = *(const frag16*)(w2s + (size_t)(ch + j * 16 + m) * 64 + kk * 32 + q * 8);
            acc2[j] = MFMA16(af2, bf2, acc2[j]);
        }
    }
    __syncthreads();
    #pragma unroll
    for (int j = 0; j < 4; ++j) {
        const int col = ch + j * 16 + m;
        const float bv = b2c[col];
        #pragma unroll
        for (int r = 0; r < 4; ++r)
            u1[(ri + q * 4 + r) * 136 + col] = f2bf(ftanh(acc2[j][r] + bv));
    }
    __syncthreads();

    // ---------------- phase 3 ----------------
    if (w < 2) {
        f32x4v acc3[13];
        #pragma unroll
        for (int j = 0; j < 13; ++j)
            #pragma unroll
            for (int r = 0; r < 4; ++r) acc3[j][r] = 0.f;
        #pragma unroll
        for (int kk = 0; kk < 2; ++kk) {
            frag16 af3 = *(const frag16*)(u1 + (w * 16 + m) * 136 + kk * 32 + q * 8);
            #pragma unroll
            for (int j = 0; j < 13; ++j) {
                frag16 bf3 = *(const frag16*)(w3s + (size_t)(j * 16 + m) * 64 + kk * 32 + q * 8);
                acc3[j] = MFMA16(af3, bf3, acc3[j]);
            }
        }
        float bcol[13];
        #pragma unroll
        for (int j = 0; j < 13; ++j) bcol[j] = b3s[j * 16 + m];
        const bool vlast = (m < 8);
        #pragma unroll
        for (int r = 0; r < 4; ++r) {
            const int gr = row0 + w * 16 + 4 * q + r;
            const int a = actions[(size_t)gr * TT + tstep];
            float lg[13], mx = -1e30f;
            #pragma unroll
            for (int j = 0; j < 13; ++j) {
                float v = acc3[j][r] + bcol[j];
                lg[j] = (j < 12 || vlast) ? v : -1e30f;
                mx = fmaxf(mx, lg[j]);
            }
            #pragma unroll
            for (int o = 1; o < 16; o <<= 1) mx = fmaxf(mx, __shfl_xor(mx, o));
            float s1 = 0.f, s2 = 0.f, sel = 0.f;
            #pragma unroll
            for (int j = 0; j < 13; ++j) {
                float e = __expf(lg[j] - mx);
                s1 += e; s2 += e * lg[j];
                sel += (j * 16 + m == a) ? lg[j] : 0.f;
            }
            #pragma unroll
            for (int o = 1; o < 16; o <<= 1) {
                s1 += __shfl_xor(s1, o); s2 += __shfl_xor(s2, o); sel += __shfl_xor(sel, o);
            }
            const float lse = mx + __logf(s1);
            if (m == 0) {
                out_lp[(size_t)gr * TT + tstep]  = sel - lse;
                out_ent[(size_t)gr * TT + tstep] = lse - s2 / s1;
            }
        }
    } else {
        const int row = (w - 2) * 16 + m;
        const unsigned short* u2row = u1 + row * 136 + 64 + q * 16;
        float pv = 0.f;
        #pragma unroll
        for (int kk = 0; kk < 16; ++kk)
            pv += bf2f(u2row[kk]) * cw3[q * 16 + kk];
        pv += __shfl_xor(pv, 16);
        pv += __shfl_xor(pv, 32);
        if (q == 0) out_v[(size_t)(row0 + row) * TT + tstep] = pv + cb3[0];
    }
}

// ---------------------------------------------------------------------------
// Fused per-step launch: blocks 0..1023 = gru_t ; blocks 1024..1535 = heads_{t-1}.
// gru block order: bm fast (bm = b & 127) so same-bn blocks share the W tile (L2).
// ---------------------------------------------------------------------------
__global__ __launch_bounds__(256, 3) void step_fused(
    const unsigned short* __restrict__ hin, unsigned short* __restrict__ hout,
    const unsigned short* __restrict__ whhb, const float* __restrict__ bhh,
    const __half* __restrict__ xg,
    const unsigned short* __restrict__ w1c, const unsigned short* __restrict__ w2s,
    const unsigned short* __restrict__ w3s,
    const float* __restrict__ b1c, const float* __restrict__ b2c,
    const float* __restrict__ b3s,
    const float* __restrict__ cw3, const float* __restrict__ cb3,
    const int* __restrict__ actions,
    float* __restrict__ out_lp, float* __restrict__ out_ent,
    float* __restrict__ out_v, int hstep)
{
    __shared__ unsigned short lds[24576];   // 48 KB -> 3 blocks/CU
    const int b = blockIdx.x;
    if (b < 1024) {
        gru_body(lds, hin, hout, whhb, bhh, xg, b & 127, b >> 7, threadIdx.x);
    } else if (hstep >= 0) {
        heads_body(lds, hin, w1c, w2s, w3s, b1c, b2c, b3s, cw3, cb3,
                   actions, out_lp, out_ent, out_v, hstep, b - 1024, threadIdx.x);
    }
}

__global__ __launch_bounds__(256) void heads_tail(
    const unsigned short* __restrict__ hx,
    const unsigned short* __restrict__ w1c, const unsigned short* __restrict__ w2s,
    const unsigned short* __restrict__ w3s,
    const float* __restrict__ b1c, const float* __restrict__ b2c,
    const float* __restrict__ b3s,
    const float* __restrict__ cw3, const float* __restrict__ cb3,
    const int* __restrict__ actions,
    float* __restrict__ out_lp, float* __restrict__ out_ent,
    float* __restrict__ out_v, int tstep)
{
    __shared__ unsigned short lds[10240];   // 20 KB
    heads_body(lds, hx, w1c, w2s, w3s, b1c, b2c, b3s, cw3, cb3,
               actions, out_lp, out_ent, out_v, tstep, blockIdx.x, threadIdx.x);
}

// ---------------------------------------------------------------------------
// One-time packing of head weights/biases.
// ---------------------------------------------------------------------------
__global__ void prep_heads(
    const float* __restrict__ aw1, const float* __restrict__ cw1,
    const float* __restrict__ aw2, const float* __restrict__ cw2,
    const float* __restrict__ aw3,
    const float* __restrict__ ab1, const float* __restrict__ cb1,
    const float* __restrict__ ab2, const float* __restrict__ cb2,
    const float* __restrict__ ab3,
    unsigned short* __restrict__ w1c, unsigned short* __restrict__ w2s,
    unsigned short* __restrict__ w3s,
    float* __restrict__ b1c, float* __restrict__ b2c, float* __restrict__ b3s)
{
    int i = blockIdx.x * 256 + threadIdx.x;
    if (i < 65536) { int r = i >> 9, c = i & 511;
        w1c[i] = f2bf(r < 64 ? aw1[r * 512 + c] : cw1[(r - 64) * 512 + c]); return; }
    i -= 65536;
    if (i < 8192) { int r = i >> 6, c = i & 63;
        w2s[i] = f2bf(r < 64 ? aw2[r * 64 + c] : cw2[(r - 64) * 64 + c]); return; }
    i -= 8192;
    if (i < 13312) { int r = i >> 6, c = i & 63;
        w3s[i] = f2bf(r < 200 ? aw3[r * 64 + c] : 0.f); return; }
    i -= 13312;
    if (i < 128) { b1c[i] = i < 64 ? ab1[i] : cb1[i - 64]; return; }
    i -= 128;
    if (i < 128) { b2c[i] = i < 64 ? ab2[i] : cb2[i - 64]; return; }
    i -= 128;
    if (i < 208) { b3s[i] = i < 200 ? ab3[i] : 0.f; return; }
}

__global__ void f2b_kernel(const float* __restrict__ s, unsigned short* __restrict__ d, int n) {
    int i = (blockIdx.x * 256 + threadIdx.x) * 4;
    if (i < n) {
        float4 v = *(const float4*)(s + i);
        ushort4 o;
        o.x = f2bf(v.x); o.y = f2bf(v.y); o.z = f2bf(v.z); o.w = f2bf(v.w);
        *(ushort4*)(d + i) = o;
    }
}

__global__ void copy_actions(const int* __restrict__ a, float* __restrict__ o, int n) {
    int i = blockIdx.x * 256 + threadIdx.x;
    if (i < n) o[i] = (float)a[i];
}

extern "C" void kernel_launch(void* const* d_in, const int* in_sizes, int n_in,
                              void* d_out, int out_size, void* d_ws, size_t ws_size,
                              hipStream_t stream)
{
    const float* images = (const float*)d_in[0];
    const int*   actions = (const int*)d_in[1];
    const float* enc_w1 = (const float*)d_in[2];
    const float* enc_b1 = (const float*)d_in[3];
    const float* enc_w2 = (const float*)d_in[4];
    const float* enc_b2 = (const float*)d_in[5];
    const float* gru_wih = (const float*)d_in[6];
    const float* gru_bih = (const float*)d_in[7];
    const float* gru_whh = (const float*)d_in[8];
    const float* gru_bhh = (const float*)d_in[9];
    const float* act_w1 = (const float*)d_in[10];
    const float* act_b1 = (const float*)d_in[11];
    const float* act_w2 = (const float*)d_in[12];
    const float* act_b2 = (const float*)d_in[13];
    const float* act_w3 = (const float*)d_in[14];
    const float* act_b3 = (const float*)d_in[15];
    const float* cri_w1 = (const float*)d_in[16];
    const float* cri_b1 = (const float*)d_in[17];
    const float* cri_w2 = (const float*)d_in[18];
    const float* cri_b2 = (const float*)d_in[19];
    const float* cri_w3 = (const float*)d_in[20];
    const float* cri_b3 = (const float*)d_in[21];

    char* ws = (char*)d_ws;
    unsigned short* imgb = (unsigned short*)ws;                    // 64MB, dead after enc1
    __half*         xg   = (__half*)ws;                            // 48MB, written by gemm3
    unsigned short* hbA  = (unsigned short*)(ws + 67108864);       // y1 / h ping (16MB)
    unsigned short* hbB  = (unsigned short*)(ws + 83886080);       // x  / h pong (16MB)
    unsigned short* w1b  = (unsigned short*)(ws + 100663296);
    unsigned short* w2b  = (unsigned short*)(ws + 102760448);
    unsigned short* wihb = (unsigned short*)(ws + 103284736);
    unsigned short* whhb = (unsigned short*)(ws + 104857600);
    unsigned short* w1c  = (unsigned short*)(ws + 106430464);      // [128,512]
    unsigned short* w2s  = (unsigned short*)(ws + 106561536);      // [128,64]
    unsigned short* w3s  = (unsigned short*)(ws + 106577920);      // [208,64]
    float*          b1c  = (float*)(ws + 106604544);
    float*          b2c  = (float*)(ws + 106605056);
    float*          b3s  = (float*)(ws + 106605568);

    float* out_act = (float*)d_out;
    float* out_lp  = out_act + (size_t)BB * TT;
    float* out_ent = out_lp  + (size_t)BB * TT;
    float* out_v   = out_ent + (size_t)BB * TT;

    dim3 blk(256);

    f2b_kernel<<<(BB * DIMG / 4 + 255) / 256, blk, 0, stream>>>(images, imgb, BB * DIMG);
    f2b_kernel<<<(512 * DIMG / 4 + 255) / 256, blk, 0, stream>>>(enc_w1, w1b, 512 * DIMG);
    f2b_kernel<<<(512 * 512 / 4 + 255) / 256, blk, 0, stream>>>(enc_w2, w2b, 512 * 512);
    f2b_kernel<<<(3 * HH * HH / 4 + 255) / 256, blk, 0, stream>>>(gru_wih, wihb, 3 * HH * HH);
    f2b_kernel<<<(3 * HH * HH / 4 + 255) / 256, blk, 0, stream>>>(gru_whh, whhb, 3 * HH * HH);
    prep_heads<<<(87504 + 255) / 256, blk, 0, stream>>>(
        act_w1, cri_w1, act_w2, cri_w2, act_w3,
        act_b1, cri_b1, act_b2, cri_b2, act_b3,
        w1c, w2s, w3s, b1c, b2c, b3s);

    // encoder + input-gate GEMMs; xg stored fp16
    gemm_bt_mfma<1, 1><<<dim3(BB / 128, 4), blk, 0, stream>>>(imgb, w1b, enc_b1, hbA, BB, 512, DIMG);
    gemm_bt_mfma<0, 1><<<dim3(BB / 128, 4), blk, 0, stream>>>(hbA, w2b, enc_b2, hbB, BB, 512, HH);
    gemm_bt_mfma<0, 2><<<dim3(BB / 128, 12), blk, 0, stream>>>(hbB, wihb, gru_bih, xg, BB, 1536, HH);

    // h0 = 0 in hbA (its y1 contents are dead after enc2)
    hipMemsetAsync(hbA, 0, (size_t)BB * HH * 2, stream);
    copy_actions<<<(BB * TT + 255) / 256, blk, 0, stream>>>(actions, out_act, BB * TT);

    for (int t = 0; t < TT; ++t) {
        const unsigned short* hin = (t & 1) ? hbB : hbA;
        unsigned short*      hout = (t & 1) ? hbA : hbB;
        step_fused<<<1536, blk, 0, stream>>>(hin, hout, whhb, gru_bhh, xg,
            w1c, w2s, w3s, b1c, b2c, b3s, cri_w3, cri_b3, actions,
            out_lp, out_ent, out_v, t - 1);
    }
    heads_tail<<<512, blk, 0, stream>>>((TT & 1) ? hbB : hbA, w1c, w2s, w3s,
        b1c, b2c, b3s, cri_w3, cri_b3, actions, out_lp, out_ent, out_v, TT - 1);
}

// Round 5
// 1417.468 us; speedup vs baseline: 1.1788x; 1.0476x over previous
//
#include <hip/hip_runtime.h>
#include <hip/hip_fp16.h>
#include <cstddef>
#include <cstdint>

#define BB 16384
#define DIMG 2048
#define HH 512
#define VOCAB 200
#define TT 20

using frag16 = __attribute__((ext_vector_type(8))) short;   // 8 x bf16 (4 VGPRs)
using f32x4v = __attribute__((ext_vector_type(4))) float;   // MFMA accumulator

#define MFMA16(a, b, c) __builtin_amdgcn_mfma_f32_16x16x32_bf16((a), (b), (c), 0, 0, 0)

__device__ __forceinline__ float bf2f(unsigned short u) {
    union { unsigned int i; float f; } c; c.i = ((unsigned int)u) << 16; return c.f;
}
__device__ __forceinline__ unsigned short f2bf(float f) {
    union { float f; unsigned int i; } c; c.f = f;
    unsigned int u = c.i;
    u = (u + 0x7FFFu + ((u >> 16) & 1u)) >> 16;   // RTNE
    return (unsigned short)u;
}
__device__ __forceinline__ float sigf(float x) { return 1.f / (1.f + __expf(-x)); }
__device__ __forceinline__ float ftanh(float x) {
    return 1.f - 2.f / (1.f + __expf(2.f * x));   // saturates correctly at +-inf
}
// async global->LDS, 16B/lane; LDS dest = wave-uniform base + lane*16
__device__ __forceinline__ void gload16(const void* g, void* l) {
    __builtin_amdgcn_global_load_lds(
        (__attribute__((address_space(1))) void*)g,
        (__attribute__((address_space(3))) void*)l, 16, 0, 0);
}

// ---------------------------------------------------------------------------
// LDS bank-conflict swizzle (T2, rule 21: both-sides-or-neither).
// [row][64B] tiles staged via global_load_lds are read as per-row 16B frags
// at (row*64 + q*16): bank = (m*16+q*4)&31 -> 8-way conflict.
// Involution: 16B chunk index ^= (row>>1)&3.
//   stage side: source chunk (t&3) -> (t&3)^((t>>3)&3)   [stage row = t>>2]
//   read  side: q -> q^((m>>1)&3)                        [read row = *16+m]
// Post-swizzle each q-group covers 8 bank-quads -> 2-way aliasing = free.
// ---------------------------------------------------------------------------

// ---------------------------------------------------------------------------
// bf16 MFMA GEMM for encoder: C = act(A[M,K] @ W[N,K]^T + bias).
// OM: 0=f32, 1=bf16, 2=f16 output.
// ---------------------------------------------------------------------------
template<int ACT, int OM>
__global__ __launch_bounds__(256) void gemm_bt_mfma(
    const unsigned short* __restrict__ A, const unsigned short* __restrict__ W,
    const float* __restrict__ bias, void* __restrict__ Cv, int M, int N, int K)
{
    __shared__ unsigned short As[128 * 32];
    __shared__ unsigned short Ws[128 * 32];
    const int t = threadIdx.x;
    const int lane = t & 63, w = t >> 6;
    const int bm = blockIdx.x, bn = blockIdx.y;
    const int wm = (w >> 1) * 64, wn = (w & 1) * 64;

    f32x4v acc[4][4];
    #pragma unroll
    for (int i = 0; i < 4; ++i)
        #pragma unroll
        for (int j = 0; j < 4; ++j)
            #pragma unroll
            for (int r = 0; r < 4; ++r) acc[i][j][r] = 0.f;

    const unsigned short* Ag  = A + (size_t)(bm * 128 + (t >> 2)) * K + (t & 3) * 8;
    const unsigned short* Ag2 = A + (size_t)(bm * 128 + 64 + (t >> 2)) * K + (t & 3) * 8;
    const unsigned short* Wg  = W + (size_t)(bn * 128 + (t >> 2)) * K + (t & 3) * 8;
    const unsigned short* Wg2 = W + (size_t)(bn * 128 + 64 + (t >> 2)) * K + (t & 3) * 8;
    char* AsB = (char*)As; char* WsB = (char*)Ws;

    const int kIters = K >> 5;
    for (int ki = 0; ki < kIters; ++ki) {
        const int k0 = ki * 32;
        gload16(Ag  + k0, AsB + w * 1024);
        gload16(Ag2 + k0, AsB + 4096 + w * 1024);
        gload16(Wg  + k0, WsB + w * 1024);
        gload16(Wg2 + k0, WsB + 4096 + w * 1024);
        __syncthreads();
        frag16 af[4], bf[4];
        #pragma unroll
        for (int i = 0; i < 4; ++i) {
            af[i] = *(const frag16*)(AsB + (wm + i * 16 + (lane & 15)) * 64 + (lane >> 4) * 16);
            bf[i] = *(const frag16*)(WsB + (wn + i * 16 + (lane & 15)) * 64 + (lane >> 4) * 16);
        }
        #pragma unroll
        for (int i = 0; i < 4; ++i)
            #pragma unroll
            for (int j = 0; j < 4; ++j)
                acc[i][j] = MFMA16(af[i], bf[j], acc[i][j]);
        __syncthreads();
    }

    #pragma unroll
    for (int j = 0; j < 4; ++j) {
        const int gn = bn * 128 + wn + j * 16 + (lane & 15);
        const float bv = bias[gn];
        #pragma unroll
        for (int i = 0; i < 4; ++i) {
            #pragma unroll
            for (int r = 0; r < 4; ++r) {
                const size_t gm = (size_t)(bm * 128 + wm + i * 16 + (lane >> 4) * 4 + r);
                float v = acc[i][j][r] + bv;
                if (ACT == 1) v = fmaxf(v, 0.f);
                if (OM == 0)      ((float*)Cv)[gm * N + gn] = v;
                else if (OM == 1) ((unsigned short*)Cv)[gm * N + gn] = f2bf(v);
                else              ((__half*)Cv)[gm * N + gn] = __float2half(v);
            }
        }
    }
}

// ---------------------------------------------------------------------------
// GRU step body (round-1 proven structure + swizzle), tile 128 rows x 64
// h-cols (x3 gates), BK=64, 256 threads, 40KB LDS, 2 barriers/iter.
// A tile 16KB [kk 8KB][row-half 4KB], W tile 24KB [kk 12KB][gate 4KB],
// both XOR-swizzled (stage source + ds_read side).
// Epilogue: two 64-row passes; xg (3x8KB fp16) + h_old (8KB) DMA'd into
// L[0..32KB), gate math from LDS, h_out repacked -> coalesced stores.
// ---------------------------------------------------------------------------
__device__ __forceinline__ void gru_body(
    unsigned short* lds,
    const unsigned short* __restrict__ hb, unsigned short* __restrict__ hob,
    const unsigned short* __restrict__ whhb, const float* __restrict__ bhh,
    const __half* __restrict__ xg, int bm, int bn, int t)
{
    char* L  = (char*)lds;
    char* LW = L + 16384;
    const int lane = t & 63, w = t >> 6;
    const int q = lane >> 4, m = lane & 15;
    const int qs = q ^ ((m >> 1) & 3);                    // swizzled read chunk
    const int scol = ((t & 3) ^ ((t >> 3) & 3)) * 8;      // swizzled stage chunk

    f32x4v acc[2][3][4];
    #pragma unroll
    for (int i = 0; i < 2; ++i)
        #pragma unroll
        for (int g = 0; g < 3; ++g)
            #pragma unroll
            for (int j = 0; j < 4; ++j)
                #pragma unroll
                for (int r = 0; r < 4; ++r) acc[i][g][j][r] = 0.f;

    // ---- K-loop staging addresses (chunk pre-swizzled) ----
    const unsigned short* Ag  = hb + (size_t)(bm * 128 + (t >> 2)) * HH + scol;
    const unsigned short* Wg0 = whhb + (size_t)(0 * HH + bn * 64 + (t >> 2)) * HH + scol;
    const unsigned short* Wg1 = whhb + (size_t)(1 * HH + bn * 64 + (t >> 2)) * HH + scol;
    const unsigned short* Wg2 = whhb + (size_t)(2 * HH + bn * 64 + (t >> 2)) * HH + scol;

    for (int ki = 0; ki < 8; ++ki) {
        const int k0 = ki * 64;
        // A tile: [kk half 8KB][row-half 4KB]
        gload16(Ag + k0,                          L + w * 1024);
        gload16(Ag + k0 + 32,                     L + 8192 + w * 1024);
        gload16(Ag + (size_t)64 * HH + k0,        L + 4096 + w * 1024);
        gload16(Ag + (size_t)64 * HH + k0 + 32,   L + 8192 + 4096 + w * 1024);
        // W tile: [kk half 12KB][gate 4KB]
        gload16(Wg0 + k0,      LW + w * 1024);
        gload16(Wg0 + k0 + 32, LW + 12288 + w * 1024);
        gload16(Wg1 + k0,      LW + 4096 + w * 1024);
        gload16(Wg1 + k0 + 32, LW + 12288 + 4096 + w * 1024);
        gload16(Wg2 + k0,      LW + 8192 + w * 1024);
        gload16(Wg2 + k0 + 32, LW + 12288 + 8192 + w * 1024);
        __syncthreads();
        #pragma unroll
        for (int kk = 0; kk < 2; ++kk) {
            frag16 af0 = *(const frag16*)(L + kk * 8192 +        (w * 16 + m) * 64 + qs * 16);
            frag16 af1 = *(const frag16*)(L + kk * 8192 + 4096 + (w * 16 + m) * 64 + qs * 16);
            #pragma unroll
            for (int g = 0; g < 3; ++g)
                #pragma unroll
                for (int j = 0; j < 4; ++j) {
                    frag16 bf = *(const frag16*)(LW + kk * 12288 + g * 4096 + (j * 16 + m) * 64 + qs * 16);
                    acc[0][g][j] = MFMA16(af0, bf, acc[0][g][j]);
                    acc[1][g][j] = MFMA16(af1, bf, acc[1][g][j]);
                }
        }
        __syncthreads();
    }

    // biases: same columns for both row-halves -> hoist
    float br[4], bz[4], bnn[4];
    #pragma unroll
    for (int j = 0; j < 4; ++j) {
        const int gc = bn * 64 + j * 16 + m;
        br[j] = bhh[gc]; bz[j] = bhh[HH + gc]; bnn[j] = bhh[2 * HH + gc];
    }

    #pragma unroll
    for (int half = 0; half < 2; ++half) {
        const int rbase = bm * 128 + half * 64;
        // ---- epilogue DMA: xg tiles at L+g*8192, h_old at L+24576 ----
        const __half* Xg = xg + (size_t)(rbase + (t >> 3)) * (3 * HH) + bn * 64 + (t & 7) * 8;
        #pragma unroll
        for (int c = 0; c < 6; ++c) {
            const int g = c >> 1, rh = c & 1;
            gload16(Xg + (size_t)rh * 32 * (3 * HH) + g * HH, L + g * 8192 + rh * 4096 + w * 1024);
        }
        const unsigned short* Hg = hb + (size_t)(rbase + (t >> 3)) * HH + bn * 64 + (t & 7) * 8;
        gload16(Hg,                   L + 24576 + w * 1024);
        gload16(Hg + (size_t)32 * HH, L + 24576 + 4096 + w * 1024);
        __syncthreads();

        unsigned short hv[4][4];
        #pragma unroll
        for (int r = 0; r < 4; ++r) {
            const int row = w * 16 + q * 4 + r;
            #pragma unroll
            for (int j = 0; j < 4; ++j) {
                const int col2 = (j * 16 + m) * 2;
                const float xr = __half2float(*(const __half*)(L + row * 128 + col2));
                const float xz = __half2float(*(const __half*)(L + 8192 + row * 128 + col2));
                const float xn = __half2float(*(const __half*)(L + 16384 + row * 128 + col2));
                const float ho = bf2f(*(const unsigned short*)(L + 24576 + row * 128 + col2));
                const float rg = sigf(xr + acc[half][0][j][r] + br[j]);
                const float zg = sigf(xz + acc[half][1][j][r] + bz[j]);
                const float ng = ftanh(xn + rg * (acc[half][2][j][r] + bnn[j]));
                hv[r][j] = f2bf((1.f - zg) * ng + zg * ho);
            }
        }
        __syncthreads();   // epilogue LDS reads done; reuse h_old area for h_out
        #pragma unroll
        for (int r = 0; r < 4; ++r) {
            const int row = w * 16 + q * 4 + r;
            #pragma unroll
            for (int j = 0; j < 4; ++j)
                *(unsigned short*)(L + 24576 + row * 128 + (j * 16 + m) * 2) = hv[r][j];
        }
        __syncthreads();
        // coalesced store: thread t -> row t>>2, 32B at col (t&3)*16
        {
            const int sr = t >> 2, sc = (t & 3) * 16;
            uint4 v0 = *(const uint4*)(L + 24576 + sr * 128 + sc * 2);
            uint4 v1 = *(const uint4*)(L + 24576 + sr * 128 + sc * 2 + 16);
            unsigned short* dst = hob + (size_t)(rbase + sr) * HH + bn * 64 + sc;
            *(uint4*)dst = v0;
            *(uint4*)(dst + 8) = v1;
        }
        __syncthreads();   // stores read L; next half's DMA overwrites it
    }
}

// ---------------------------------------------------------------------------
// Heads body: 32 batch rows per block, BK=64 phase-1 staging (swizzled).
// ---------------------------------------------------------------------------
__device__ __forceinline__ void heads_body(
    unsigned short* lds, const unsigned short* __restrict__ hxb,
    const unsigned short* __restrict__ w1c, const unsigned short* __restrict__ w2s,
    const unsigned short* __restrict__ w3s,
    const float* __restrict__ b1c, const float* __restrict__ b2c,
    const float* __restrict__ b3s,
    const float* __restrict__ cw3, const float* __restrict__ cb3,
    const int* __restrict__ actions,
    float* __restrict__ out_lp, float* __restrict__ out_ent,
    float* __restrict__ out_v, int tstep, int hblk, int t)
{
    char* sH = (char*)lds;              // 4 KB: two 2 KB kk-halves [32][64B]
    char* sW = (char*)lds + 4096;       // 16 KB: two 8 KB kk-halves [128][64B]
    unsigned short* u1 = lds;           // aliased after phase 1: [32][136]
    const int lane = t & 63, w = t >> 6;
    const int q = lane >> 4, m = lane & 15;
    const int qs = q ^ ((m >> 1) & 3);                    // swizzled read chunk
    const int scol = ((t & 3) ^ ((t >> 3) & 3)) * 8;      // swizzled stage chunk
    const int row0 = hblk * 32;
    const int ri = (w & 1) * 16, ch = (w >> 1) * 64;

    // ---------------- phase 1: u1 = tanh(h @ w1c^T + b1c) ----------------
    f32x4v acc[4];
    #pragma unroll
    for (int j = 0; j < 4; ++j)
        #pragma unroll
        for (int r = 0; r < 4; ++r) acc[j][r] = 0.f;

    const unsigned short* Hrow = hxb + (size_t)(row0 + ((t >> 2) & 31)) * HH
                                 + (t >> 7) * 32 + scol;
    const unsigned short* Wrow[4]; int WldsOff[4];
    #pragma unroll
    for (int c = 0; c < 4; ++c) {
        const int kk = c & 1, rb = (c >> 1) * 64;
        Wrow[c] = w1c + (size_t)(rb + (t >> 2)) * HH + kk * 32 + scol;
        WldsOff[c] = kk * 8192 + rb * 64;
    }

    for (int ki = 0; ki < 8; ++ki) {
        const int k0 = ki * 64;
        gload16(Hrow + k0, sH + w * 1024);
        #pragma unroll
        for (int c = 0; c < 4; ++c)
            gload16(Wrow[c] + k0, sW + WldsOff[c] + w * 1024);
        __syncthreads();
        #pragma unroll
        for (int kk = 0; kk < 2; ++kk) {
            frag16 af = *(const frag16*)(sH + kk * 2048 + (ri + m) * 64 + qs * 16);
            #pragma unroll
            for (int j = 0; j < 4; ++j) {
                frag16 bf = *(const frag16*)(sW + kk * 8192 + (ch + j * 16 + m) * 64 + qs * 16);
                acc[j] = MFMA16(af, bf, acc[j]);
            }
        }
        __syncthreads();
    }
    #pragma unroll
    for (int j = 0; j < 4; ++j) {
        const int col = ch + j * 16 + m;
        const float bv = b1c[col];
        #pragma unroll
        for (int r = 0; r < 4; ++r)
            u1[(ri + q * 4 + r) * 136 + col] = f2bf(ftanh(acc[j][r] + bv));
    }
    __syncthreads();

    // ---------------- phase 2: u2 (actor ch=0 / critic ch=64) ----------------
    f32x4v acc2[4];
    #pragma unroll
    for (int j = 0; j < 4; ++j)
        #pragma unroll
        for (int r = 0; r < 4; ++r) acc2[j][r] = 0.f;
    #pragma unroll
    for (int kk = 0; kk < 2; ++kk) {
        frag16 af2 = *(const frag16*)(u1 + (ri + m) * 136 + ch + kk * 32 + q * 8);
        #pragma unroll
        for (int j = 0; j < 4; ++j) {
            frag16 bf2 = *(const frag16*)(w2s + (size_t)(ch + j * 16 + m) * 64 + kk * 32 + q * 8);
            acc2[j] = MFMA16(af2, bf2, acc2[j]);
        }
    }
    __syncthreads();
    #pragma unroll
    for (int j = 0; j < 4; ++j) {
        const int col = ch + j * 16 + m;
        const float bv = b2c[col];
        #pragma unroll
        for (int r = 0; r < 4; ++r)
            u1[(ri + q * 4 + r) * 136 + col] = f2bf(ftanh(acc2[j][r] + bv));
    }
    __syncthreads();

    // ---------------- phase 3 ----------------
    if (w < 2) {
        f32x4v acc3[13];
        #pragma unroll
        for (int j = 0; j < 13; ++j)
            #pragma unroll
            for (int r = 0; r < 4; ++r) acc3[j][r] = 0.f;
        #pragma unroll
        for (int kk = 0; kk < 2; ++kk) {
            frag16 af3 = *(const frag16*)(u1 + (w * 16 + m) * 136 + kk * 32 + q * 8);
            #pragma unroll
            for (int j = 0; j < 13; ++j) {
                frag16 bf3 = *(const frag16*)(w3s + (size_t)(j * 16 + m) * 64 + kk * 32 + q * 8);
                acc3[j] = MFMA16(af3, bf3, acc3[j]);
            }
        }
        float bcol[13];
        #pragma unroll
        for (int j = 0; j < 13; ++j) bcol[j] = b3s[j * 16 + m];
        const bool vlast = (m < 8);
        #pragma unroll
        for (int r = 0; r < 4; ++r) {
            const int gr = row0 + w * 16 + 4 * q + r;
            const int a = actions[(size_t)gr * TT + tstep];
            float lg[13], mx = -1e30f;
            #pragma unroll
            for (int j = 0; j < 13; ++j) {
                float v = acc3[j][r] + bcol[j];
                lg[j] = (j < 12 || vlast) ? v : -1e30f;
                mx = fmaxf(mx, lg[j]);
            }
            #pragma unroll
            for (int o = 1; o < 16; o <<= 1) mx = fmaxf(mx, __shfl_xor(mx, o));
            float s1 = 0.f, s2 = 0.f, sel = 0.f;
            #pragma unroll
            for (int j = 0; j < 13; ++j) {
                float e = __expf(lg[j] - mx);
                s1 += e; s2 += e * lg[j];
                sel += (j * 16 + m == a) ? lg[j] : 0.f;
            }
            #pragma unroll
            for (int o = 1; o < 16; o <<= 1) {
                s1 += __shfl_xor(s1, o); s2 += __shfl_xor(s2, o); sel += __shfl_xor(sel, o);
            }
            const float lse = mx + __logf(s1);
            if (m == 0) {
                out_lp[(size_t)gr * TT + tstep]  = sel - lse;
                out_ent[(size_t)gr * TT + tstep] = lse - s2 / s1;
            }
        }
    } else {
        const int row = (w - 2) * 16 + m;
        const unsigned short* u2row = u1 + row * 136 + 64 + q * 16;
        float pv = 0.f;
        #pragma unroll
        for (int kk = 0; kk < 16; ++kk)
            pv += bf2f(u2row[kk]) * cw3[q * 16 + kk];
        pv += __shfl_xor(pv, 16);
        pv += __shfl_xor(pv, 32);
        if (q == 0) out_v[(size_t)(row0 + row) * TT + tstep] = pv + cb3[0];
    }
}

// ---------------------------------------------------------------------------
// Fused per-step launch: blocks 0..1023 = gru_t ; blocks 1024..1535 = heads_{t-1}.
// GRU block map (XCD round-robin = b%8 assumed): bm = ((b>>6)<<3)|(b&7),
// bn = (b>>3)&7 -> each XCD runs one bm-group's 8 bn-tiles back-to-back:
// A rows (128KB) stay L2-hot across their 8 uses, whh (1.5MB) L2-resident.
// Cuts h re-read L3 traffic 8x so xg (48MB) stays L3-resident across steps.
// ---------------------------------------------------------------------------
__global__ __launch_bounds__(256, 3) void step_fused(
    const unsigned short* __restrict__ hin, unsigned short* __restrict__ hout,
    const unsigned short* __restrict__ whhb, const float* __restrict__ bhh,
    const __half* __restrict__ xg,
    const unsigned short* __restrict__ w1c, const unsigned short* __restrict__ w2s,
    const unsigned short* __restrict__ w3s,
    const float* __restrict__ b1c, const float* __restrict__ b2c,
    const float* __restrict__ b3s,
    const float* __restrict__ cw3, const float* __restrict__ cb3,
    const int* __restrict__ actions,
    float* __restrict__ out_lp, float* __restrict__ out_ent,
    float* __restrict__ out_v, int hstep)
{
    __shared__ unsigned short lds[20480];   // 40 KB
    const int b = blockIdx.x;
    if (b < 1024) {
        const int bm = ((b >> 6) << 3) | (b & 7);
        const int bn = (b >> 3) & 7;
        gru_body(lds, hin, hout, whhb, bhh, xg, bm, bn, threadIdx.x);
    } else if (hstep >= 0) {
        heads_body(lds, hin, w1c, w2s, w3s, b1c, b2c, b3s, cw3, cb3,
                   actions, out_lp, out_ent, out_v, hstep, b - 1024, threadIdx.x);
    }
}

__global__ __launch_bounds__(256) void heads_tail(
    const unsigned short* __restrict__ hx,
    const unsigned short* __restrict__ w1c, const unsigned short* __restrict__ w2s,
    const unsigned short* __restrict__ w3s,
    const float* __restrict__ b1c, const float* __restrict__ b2c,
    const float* __restrict__ b3s,
    const float* __restrict__ cw3, const float* __restrict__ cb3,
    const int* __restrict__ actions,
    float* __restrict__ out_lp, float* __restrict__ out_ent,
    float* __restrict__ out_v, int tstep)
{
    __shared__ unsigned short lds[10240];   // 20 KB
    heads_body(lds, hx, w1c, w2s, w3s, b1c, b2c, b3s, cw3, cb3,
               actions, out_lp, out_ent, out_v, tstep, blockIdx.x, threadIdx.x);
}

// ---------------------------------------------------------------------------
// One-time packing of head weights/biases.
// ---------------------------------------------------------------------------
__global__ void prep_heads(
    const float* __restrict__ aw1, const float* __restrict__ cw1,
    const float* __restrict__ aw2, const float* __restrict__ cw2,
    const float* __restrict__ aw3,
    const float* __restrict__ ab1, const float* __restrict__ cb1,
    const float* __restrict__ ab2, const float* __restrict__ cb2,
    const float* __restrict__ ab3,
    unsigned short* __restrict__ w1c, unsigned short* __restrict__ w2s,
    unsigned short* __restrict__ w3s,
    float* __restrict__ b1c, float* __restrict__ b2c, float* __restrict__ b3s)
{
    int i = blockIdx.x * 256 + threadIdx.x;
    if (i < 65536) { int r = i >> 9, c = i & 511;
        w1c[i] = f2bf(r < 64 ? aw1[r * 512 + c] : cw1[(r - 64) * 512 + c]); return; }
    i -= 65536;
    if (i < 8192) { int r = i >> 6, c = i & 63;
        w2s[i] = f2bf(r < 64 ? aw2[r * 64 + c] : cw2[(r - 64) * 64 + c]); return; }
    i -= 8192;
    if (i < 13312) { int r = i >> 6, c = i & 63;
        w3s[i] = f2bf(r < 200 ? aw3[r * 64 + c] : 0.f); return; }
    i -= 13312;
    if (i < 128) { b1c[i] = i < 64 ? ab1[i] : cb1[i - 64]; return; }
    i -= 128;
    if (i < 128) { b2c[i] = i < 64 ? ab2[i] : cb2[i - 64]; return; }
    i -= 128;
    if (i < 208) { b3s[i] = i < 200 ? ab3[i] : 0.f; return; }
}

__global__ void f2b_kernel(const float* __restrict__ s, unsigned short* __restrict__ d, int n) {
    int i = (blockIdx.x * 256 + threadIdx.x) * 4;
    if (i < n) {
        float4 v = *(const float4*)(s + i);
        ushort4 o;
        o.x = f2bf(v.x); o.y = f2bf(v.y); o.z = f2bf(v.z); o.w = f2bf(v.w);
        *(ushort4*)(d + i) = o;
    }
}

__global__ void copy_actions(const int* __restrict__ a, float* __restrict__ o, int n) {
    int i = blockIdx.x * 256 + threadIdx.x;
    if (i < n) o[i] = (float)a[i];
}

extern "C" void kernel_launch(void* const* d_in, const int* in_sizes, int n_in,
                              void* d_out, int out_size, void* d_ws, size_t ws_size,
                              hipStream_t stream)
{
    const float* images = (const float*)d_in[0];
    const int*   actions = (const int*)d_in[1];
    const float* enc_w1 = (const float*)d_in[2];
    const float* enc_b1 = (const float*)d_in[3];
    const float* enc_w2 = (const float*)d_in[4];
    const float* enc_b2 = (const float*)d_in[5];
    const float* gru_wih = (const float*)d_in[6];
    const float* gru_bih = (const float*)d_in[7];
    const float* gru_whh = (const float*)d_in[8];
    const float* gru_bhh = (const float*)d_in[9];
    const float* act_w1 = (const float*)d_in[10];
    const float* act_b1 = (const float*)d_in[11];
    const float* act_w2 = (const float*)d_in[12];
    const float* act_b2 = (const float*)d_in[13];
    const float* act_w3 = (const float*)d_in[14];
    const float* act_b3 = (const float*)d_in[15];
    const float* cri_w1 = (const float*)d_in[16];
    const float* cri_b1 = (const float*)d_in[17];
    const float* cri_w2 = (const float*)d_in[18];
    const float* cri_b2 = (const float*)d_in[19];
    const float* cri_w3 = (const float*)d_in[20];
    const float* cri_b3 = (const float*)d_in[21];

    char* ws = (char*)d_ws;
    unsigned short* imgb = (unsigned short*)ws;                    // 64MB, dead after enc1
    __half*         xg   = (__half*)ws;                            // 48MB, written by gemm3
    unsigned short* hbA  = (unsigned short*)(ws + 67108864);       // y1 / h ping (16MB)
    unsigned short* hbB  = (unsigned short*)(ws + 83886080);       // x  / h pong (16MB)
    unsigned short* w1b  = (unsigned short*)(ws + 100663296);
    unsigned short* w2b  = (unsigned short*)(ws + 102760448);
    unsigned short* wihb = (unsigned short*)(ws + 103284736);
    unsigned short* whhb = (unsigned short*)(ws + 104857600);
    unsigned short* w1c  = (unsigned short*)(ws + 106430464);      // [128,512]
    unsigned short* w2s  = (unsigned short*)(ws + 106561536);      // [128,64]
    unsigned short* w3s  = (unsigned short*)(ws + 106577920);      // [208,64]
    float*          b1c  = (float*)(ws + 106604544);
    float*          b2c  = (float*)(ws + 106605056);
    float*          b3s  = (float*)(ws + 106605568);

    float* out_act = (float*)d_out;
    float* out_lp  = out_act + (size_t)BB * TT;
    float* out_ent = out_lp  + (size_t)BB * TT;
    float* out_v   = out_ent + (size_t)BB * TT;

    dim3 blk(256);

    f2b_kernel<<<(BB * DIMG / 4 + 255) / 256, blk, 0, stream>>>(images, imgb, BB * DIMG);
    f2b_kernel<<<(512 * DIMG / 4 + 255) / 256, blk, 0, stream>>>(enc_w1, w1b, 512 * DIMG);
    f2b_kernel<<<(512 * 512 / 4 + 255) / 256, blk, 0, stream>>>(enc_w2, w2b, 512 * 512);
    f2b_kernel<<<(3 * HH * HH / 4 + 255) / 256, blk, 0, stream>>>(gru_wih, wihb, 3 * HH * HH);
    f2b_kernel<<<(3 * HH * HH / 4 + 255) / 256, blk, 0, stream>>>(gru_whh, whhb, 3 * HH * HH);
    prep_heads<<<(87504 + 255) / 256, blk, 0, stream>>>(
        act_w1, cri_w1, act_w2, cri_w2, act_w3,
        act_b1, cri_b1, act_b2, cri_b2, act_b3,
        w1c, w2s, w3s, b1c, b2c, b3s);

    // encoder + input-gate GEMMs; xg stored fp16
    gemm_bt_mfma<1, 1><<<dim3(BB / 128, 4), blk, 0, stream>>>(imgb, w1b, enc_b1, hbA, BB, 512, DIMG);
    gemm_bt_mfma<0, 1><<<dim3(BB / 128, 4), blk, 0, stream>>>(hbA, w2b, enc_b2, hbB, BB, 512, HH);
    gemm_bt_mfma<0, 2><<<dim3(BB / 128, 12), blk, 0, stream>>>(hbB, wihb, gru_bih, xg, BB, 1536, HH);

    // h0 = 0 in hbA (its y1 contents are dead after enc2)
    hipMemsetAsync(hbA, 0, (size_t)BB * HH * 2, stream);
    copy_actions<<<(BB * TT + 255) / 256, blk, 0, stream>>>(actions, out_act, BB * TT);

    for (int t = 0; t < TT; ++t) {
        const unsigned short* hin = (t & 1) ? hbB : hbA;
        unsigned short*      hout = (t & 1) ? hbA : hbB;
        step_fused<<<1536, blk, 0, stream>>>(hin, hout, whhb, gru_bhh, xg,
            w1c, w2s, w3s, b1c, b2c, b3s, cri_w3, cri_b3, actions,
            out_lp, out_ent, out_v, t - 1);
    }
    heads_tail<<<512, blk, 0, stream>>>((TT & 1) ? hbB : hbA, w1c, w2s, w3s,
        b1c, b2c, b3s, cri_w3, cri_b3, actions, out_lp, out_ent, out_v, TT - 1);
}